// Round 4
// baseline (733.402 us; speedup 1.0000x reference)
//
#include <hip/hip_runtime.h>
#include <math.h>

#define TPB 256

// ---- analytic Wigner-3j constants (verified R1: absmax 0.0156) ----
#define R10   0.31622776601683794f  // 1/sqrt(10)
#define R30   0.18257418583505536f  // 1/sqrt(30)
#define R30x2 0.36514837167011072f  // 2/sqrt(30)
#define C222_SIGN (1.0f)            // verified R1
#define CCA (C222_SIGN * 0.23904572186687872f) // 2/sqrt(70)
#define CCB (C222_SIGN * 0.20701966780270623f) // sqrt(3/70)
#define CCC (C222_SIGN * 0.11952286093343936f) // 1/sqrt(70)

__device__ __forceinline__ void atomAddF(float* p, float v) {
    __hip_atomic_fetch_add(p, v, __ATOMIC_RELAXED, __HIP_MEMORY_SCOPE_AGENT);
}

template<int M>
__device__ __forceinline__ void fc_eval(const float* sW1T, const float* sW2,
                                        const float emb[12], float* acc)
{
#pragma unroll
    for (int m = 0; m < M; ++m) acc[m] = 0.f;
#pragma unroll 2
    for (int j = 0; j < 64; ++j) {
        const float4* w1r = (const float4*)(sW1T + j * 12);
        float4 A = w1r[0], B = w1r[1], C = w1r[2];
        float t = A.x*emb[0] + A.y*emb[1] + A.z*emb[2] + A.w*emb[3]
                + B.x*emb[4] + B.y*emb[5] + B.z*emb[6] + B.w*emb[7]
                + C.x*emb[8] + C.y*emb[9];
        t = fmaxf(t, 0.f);
        const float4* w2r = (const float4*)(sW2 + j * M);
#pragma unroll
        for (int q = 0; q < M / 4; ++q) {
            float4 V = w2r[q];
            acc[4*q+0] = fmaf(t, V.x, acc[4*q+0]);
            acc[4*q+1] = fmaf(t, V.y, acc[4*q+1]);
            acc[4*q+2] = fmaf(t, V.z, acc[4*q+2]);
            acc[4*q+3] = fmaf(t, V.w, acc[4*q+3]);
        }
    }
}

// 6-step segmented inclusive scan (sum toward higher lanes) over 36 regs.
// dist = lane - segment_head_lane. Wave-synchronous, no barriers.
__device__ __forceinline__ void segscan36(float* b, int dist) {
    for (int s = 1; s < 64; s <<= 1) {
        bool c = dist >= s;
#pragma unroll
        for (int j = 0; j < 36; ++j) {
            float t = __shfl_up(b[j], s);
            if (c) b[j] += t;
        }
    }
}

// ============ node-record precompute: {pos[3], xs, xp[9], xd[25], pad[2]} ============
__global__ __launch_bounds__(256) void build_rec_kernel(const float* __restrict__ f_in,
                                                        const float* __restrict__ pos,
                                                        float* __restrict__ rec, int N) {
    int n = blockIdx.x * 256 + threadIdx.x;
    if (n >= N) return;
    const float* f = f_in + (size_t)n * 162;
    float* r = rec + (size_t)n * 40;
    r[0] = pos[n * 3 + 0]; r[1] = pos[n * 3 + 1]; r[2] = pos[n * 3 + 2];
    float2 v0 = *(const float2*)f;
    r[3] = v0.x + v0.y;
#pragma unroll
    for (int u = 0; u < 3; ++u)
#pragma unroll
        for (int v = 0; v < 3; ++v) {
            float2 a = *(const float2*)(f + ((1 + u) * 9 + (1 + v)) * 2);
            r[4 + u * 3 + v] = a.x + a.y;
        }
#pragma unroll
    for (int u = 0; u < 5; ++u)
#pragma unroll
        for (int v = 0; v < 5; ++v) {
            float2 a = *(const float2*)(f + ((4 + u) * 9 + (4 + v)) * 2);
            r[13 + u * 5 + v] = a.x + a.y;
        }
    r[38] = 0.f; r[39] = 0.f;
}

// ============ histogram of col ============
__global__ __launch_bounds__(256) void count_kernel(const int* __restrict__ col,
                                                    int* __restrict__ cnt, int E) {
    int e = blockIdx.x * 256 + threadIdx.x;
    if (e < E) atomicAdd(&cnt[col[e]], 1);
}

// ============ exclusive scan -> cursor (1 block, shuffle-based) ============
__global__ __launch_bounds__(1024) void scan_kernel(const int* __restrict__ cnt,
                                                    int* __restrict__ cursor, int N) {
    __shared__ int wsum[16];
    const int tid = threadIdx.x;
    const int lane = tid & 63;
    const int wv = tid >> 6;
    int carry = 0;
    for (int base = 0; base < N; base += 4096) {
        int i0 = base + tid * 4;
        int v0 = (i0 + 0 < N) ? cnt[i0 + 0] : 0;
        int v1 = (i0 + 1 < N) ? cnt[i0 + 1] : 0;
        int v2 = (i0 + 2 < N) ? cnt[i0 + 2] : 0;
        int v3 = (i0 + 3 < N) ? cnt[i0 + 3] : 0;
        int s = v0 + v1 + v2 + v3;
        int sc = s;
        for (int d = 1; d < 64; d <<= 1) {
            int t = __shfl_up(sc, d);
            if (lane >= d) sc += t;
        }
        if (lane == 63) wsum[wv] = sc;
        __syncthreads();
        int woff = carry, tot = carry;
#pragma unroll
        for (int w = 0; w < 16; ++w) {
            int x = wsum[w];
            if (w < wv) woff += x;
            tot += x;
        }
        int excl = woff + (sc - s);
        if (i0 + 0 < N) cursor[i0 + 0] = excl;
        excl += v0;
        if (i0 + 1 < N) cursor[i0 + 1] = excl;
        excl += v1;
        if (i0 + 2 < N) cursor[i0 + 2] = excl;
        excl += v2;
        if (i0 + 3 < N) cursor[i0 + 3] = excl;
        carry = tot;
        __syncthreads();
    }
}

// ============ permute edges into sorted-by-col order (packed int2) ============
__global__ __launch_bounds__(256) void permute_kernel(const int* __restrict__ eidx,
                                                      int* __restrict__ cursor,
                                                      int2* __restrict__ edges, int E) {
    int e = blockIdx.x * 256 + threadIdx.x;
    if (e < E) {
        int c = eidx[E + e];
        int p = atomicAdd(&cursor[c], 1);
        edges[p] = make_int2(eidx[e], c);
    }
}

// ============ fused: per-edge compute + wave-local segmented reduce ============
__global__ __launch_bounds__(TPB, 3) void fused_wave_kernel(
    const float* __restrict__ rec,
    const int2*  __restrict__ edges,
    const float* __restrict__ W1s_g, const float* __restrict__ W2s_g,
    const float* __restrict__ W1p_g, const float* __restrict__ W2p_g,
    const float* __restrict__ W1d_g, const float* __restrict__ W2d_g,
    float* __restrict__ out,
    int E, int numTiles, float snorm)
{
    __shared__ __align__(16) float smem[11264];
    float* tW1  = smem;            // 3 x (64x12), W1^T padded 10->12
    float* sW2s = smem + 2304;     // 64x12
    float* sW2p = smem + 3072;     // 64x48
    float* sW2d = smem + 6144;     // 64x80

    const int tid = threadIdx.x;
    const int lane = tid & 63;
    const float base = 0.05590169943749474f * snorm; // sqrt2/(8*sqrt10) * snorm

    // ---- stage all weights ONCE per block ----
    for (int idx = tid; idx < 768; idx += TPB) {
        int j = idx / 12, i = idx - j * 12;
        tW1[idx]        = (i < 10) ? W1s_g[i * 64 + j] : 0.f;
        tW1[768 + idx]  = (i < 10) ? W1p_g[i * 64 + j] : 0.f;
        tW1[1536 + idx] = (i < 10) ? W1d_g[i * 64 + j] : 0.f;
        sW2s[idx] = W2s_g[idx] * base;
    }
    for (int idx = tid; idx < 3072; idx += TPB) {
        int m = idx % 48;
        float k = (m < 12) ? 0.40824829046386307f
                : (m < 24) ? 0.33333333333333333f
                : (m < 36) ? 1.29099444873580560f
                           : 0.70710678118654752f;
        sW2p[idx] = W2p_g[idx] * (base * k);
    }
    for (int idx = tid; idx < 5120; idx += TPB) {
        int m = idx % 80;
        float k = (m < 20) ? 0.31622776601683794f
                : (m < 40) ? 0.77459666924148340f
                : (m < 60) ? 0.2f
                           : 0.70710678118654752f;
        sW2d[idx] = W2d_g[idx] * (base * k);
    }
    __syncthreads();

    for (int tile = blockIdx.x; tile < numTiles; tile += gridDim.x) {
        const int p = tile * TPB + tid;
        const bool valid = p < E;
        int2 ed = valid ? edges[p] : make_int2(0, 0x7fffffff);
        const int row = ed.x;
        const int col = ed.y;               // 0x7fffffff on invalid lanes
        const int colIdx = valid ? col : 0;

        // ---- wave-local segmentation (no barriers) ----
        int prevCol = __shfl_up(col, 1);
        bool head = (lane == 0) || (col != prevCol);
        unsigned long long m = __ballot(head);
        unsigned long long below = m & ((2ull << lane) - 1ull);
        const int hd = 63 - __builtin_clzll(below);
        const bool tail = (lane == 63) ? true : (((m >> (lane + 1)) & 1ull) != 0);
        const int dist = lane - hd;

        int clf = 0, crf = 0;
        if (lane == 0 && valid && p > 0)       clf = (edges[p - 1].y == col);
        if (lane == 63 && valid && (p + 1) < E) crf = (edges[p + 1].y == col);
        const int contL = __shfl(clf, 0);
        const int contR = __shfl(crf, 63);
        const bool partial = (hd == 0 && contL) || (lane == 63 && contR);
        const bool doWrite = tail && valid;

        // ---- gather node record (10 x float4, 160B) + col pos ----
        const float* rr = rec + (size_t)row * 40;
        float R[40];
#pragma unroll
        for (int i = 0; i < 10; ++i) ((float4*)R)[i] = ((const float4*)rr)[i];
        const float4 qc = *(const float4*)(rec + (size_t)colIdx * 40);

        float ex = R[0] - qc.x, ey = R[1] - qc.y, ez = R[2] - qc.z;
        float r = sqrtf(ex * ex + ey * ey + ez * ez + 1e-12f);
        float rinv = 1.0f / r;
        float x = ex * rinv, y = ey * rinv, z = ez * rinv;

        float sh1 = 1.7320508075688772f * x;
        float sh2 = 1.7320508075688772f * y;
        float sh3 = 1.7320508075688772f * z;
        float sh4 = 3.8729833462074170f * x * z;
        float sh5 = 3.8729833462074170f * x * y;
        float sh6 = 1.1180339887498949f * (2.f * y * y - x * x - z * z);
        float sh7 = 3.8729833462074170f * y * z;
        float sh8 = 1.9364916731037085f * (z * z - x * x);

        float emb[12];
        {
            const float F = (float)(1.14136 * 7.38905609893065 * 3.1622776601683795);
            const float inv_step = 2.2f;
#pragma unroll
            for (int i = 0; i < 10; ++i) {
                float v = (float)(i + 1) * (5.0f / 11.0f);
                float d = (r - v) * inv_step;
                float d2 = d * d;
                emb[i] = (d2 < 1.0f) ? F * expf(-2.0f / (1.0f - d2)) : 0.f;
            }
            emb[10] = 0.f; emb[11] = 0.f;
        }

        float b[36] __attribute__((aligned(16)));

        auto emit = [&](int obase) {
            if (doWrite) {
                float* o = out + (size_t)col * 108 + obase;
                if (partial) {
#pragma unroll
                    for (int j = 0; j < 36; ++j) atomAddF(o + j, b[j]);
                } else {
#pragma unroll
                    for (int q = 0; q < 9; ++q) ((float4*)o)[q] = ((const float4*)b)[q];
                }
            }
        };

        // ================= S path (out 0..35) =================
        {
            float ws[12];
            fc_eval<12>(tW1, sW2s, emb, ws);
            float X = R[3];
#pragma unroll
            for (int w = 0; w < 4; ++w) {
                b[w] = X * ws[w];
                float t1 = X * ws[4 + w];
                b[4 + w * 3 + 0] = t1 * sh1;
                b[4 + w * 3 + 1] = t1 * sh2;
                b[4 + w * 3 + 2] = t1 * sh3;
                float t2 = X * ws[8 + w];
                b[16 + w * 5 + 0] = t2 * sh4;
                b[16 + w * 5 + 1] = t2 * sh5;
                b[16 + w * 5 + 2] = t2 * sh6;
                b[16 + w * 5 + 3] = t2 * sh7;
                b[16 + w * 5 + 4] = t2 * sh8;
            }
        }
        segscan36(b, dist);
        emit(0);

        // ================= P path (out 36..71) =================
        {
            float wp[48];
            fc_eval<48>(tW1 + 768, sW2p, emb, wp);
            float* op0 = b;       // 4
            float* op1 = b + 4;   // 12
            float* op2 = b + 16;  // 20
#pragma unroll
            for (int t = 0; t < 36; ++t) b[t] = 0.f;
#pragma unroll
            for (int u = 0; u < 3; ++u) {
                float x0 = R[4 + u * 3 + 0], x1 = R[4 + u * 3 + 1], x2 = R[4 + u * 3 + 2];
                float dot = x0 * sh1 + x1 * sh2 + x2 * sh3;
                float ya0 = R10 * (x0 * sh3 + x2 * sh1);
                float ya1 = R10 * (x0 * sh2 + x1 * sh1);
                float ya2 = R30 * (2.f * x1 * sh2 - x0 * sh1 - x2 * sh3);
                float ya3 = R10 * (x1 * sh3 + x2 * sh2);
                float ya4 = R10 * (x2 * sh3 - x0 * sh1);
                float yb0 = R10 * (x2 * sh4 + x1 * sh5 - x0 * sh8) - R30 * x0 * sh6;
                float yb1 = R10 * (x0 * sh5 + x2 * sh7) + R30x2 * x1 * sh6;
                float yb2 = R10 * (x0 * sh4 + x1 * sh7 + x2 * sh8) - R30 * x2 * sh6;
#pragma unroll
                for (int w = 0; w < 4; ++w) {
                    float wa = wp[u * 4 + w];
                    float wb = wp[12 + u * 4 + w];
                    float wc = wp[24 + u * 4 + w];
                    float wd2 = wp[36 + u * 4 + w];
                    op0[w] = fmaf(dot, wb, op0[w]);
                    op1[w * 3 + 0] = fmaf(x0, wa, fmaf(yb0, wd2, op1[w * 3 + 0]));
                    op1[w * 3 + 1] = fmaf(x1, wa, fmaf(yb1, wd2, op1[w * 3 + 1]));
                    op1[w * 3 + 2] = fmaf(x2, wa, fmaf(yb2, wd2, op1[w * 3 + 2]));
                    op2[w * 5 + 0] = fmaf(ya0, wc, op2[w * 5 + 0]);
                    op2[w * 5 + 1] = fmaf(ya1, wc, op2[w * 5 + 1]);
                    op2[w * 5 + 2] = fmaf(ya2, wc, op2[w * 5 + 2]);
                    op2[w * 5 + 3] = fmaf(ya3, wc, op2[w * 5 + 3]);
                    op2[w * 5 + 4] = fmaf(ya4, wc, op2[w * 5 + 4]);
                }
            }
        }
        segscan36(b, dist);
        emit(36);

        // ================= D path (out 72..107) =================
        {
            float wd[80];
            fc_eval<80>(tW1 + 1536, sW2d, emb, wd);
            float* od0 = b;       // 4
            float* od1 = b + 4;   // 12
            float* od2 = b + 16;  // 20
#pragma unroll
            for (int t = 0; t < 36; ++t) b[t] = 0.f;
#pragma unroll
            for (int u = 0; u < 5; ++u) {
                float x0 = R[13 + u * 5 + 0], x1 = R[13 + u * 5 + 1], x2 = R[13 + u * 5 + 2];
                float x3 = R[13 + u * 5 + 3], x4 = R[13 + u * 5 + 4];
                float dot = x0 * sh4 + x1 * sh5 + x2 * sh6 + x3 * sh7 + x4 * sh8;
                float yb0 = R10 * (x0 * sh3 + x1 * sh2 - x4 * sh1) - R30 * x2 * sh1;
                float yb1 = R10 * (x1 * sh1 + x3 * sh3) + R30x2 * x2 * sh2;
                float yb2 = R10 * (x0 * sh1 + x3 * sh2 + x4 * sh3) - R30 * x2 * sh3;
                float yc0 = CCA * (x2 * sh4 + x0 * sh6) - CCB * (x1 * sh7 + x3 * sh5);
                float yc1 = CCB * (x1 * sh8 + x4 * sh5 - x0 * sh7 - x3 * sh4)
                          - CCC * (x1 * sh6 + x2 * sh5);
                float yc2 = CCA * (x0 * sh4 - x2 * sh6 + x4 * sh8)
                          - CCC * (x1 * sh5 + x3 * sh7);
                float yc3 = -CCB * (x0 * sh5 + x1 * sh4 + x3 * sh8 + x4 * sh7)
                          - CCC * (x2 * sh7 + x3 * sh6);
                float yc4 = CCB * (x1 * sh5 - x3 * sh7) + CCA * (x2 * sh8 + x4 * sh6);
#pragma unroll
                for (int w = 0; w < 4; ++w) {
                    float wa = wd[u * 4 + w];
                    float wb = wd[20 + u * 4 + w];
                    float wc = wd[40 + u * 4 + w];
                    float we = wd[60 + u * 4 + w];
                    od0[w] = fmaf(dot, wc, od0[w]);
                    od1[w * 3 + 0] = fmaf(yb0, wb, od1[w * 3 + 0]);
                    od1[w * 3 + 1] = fmaf(yb1, wb, od1[w * 3 + 1]);
                    od1[w * 3 + 2] = fmaf(yb2, wb, od1[w * 3 + 2]);
                    od2[w * 5 + 0] = fmaf(x0, wa, fmaf(yc0, we, od2[w * 5 + 0]));
                    od2[w * 5 + 1] = fmaf(x1, wa, fmaf(yc1, we, od2[w * 5 + 1]));
                    od2[w * 5 + 2] = fmaf(x2, wa, fmaf(yc2, we, od2[w * 5 + 2]));
                    od2[w * 5 + 3] = fmaf(x3, wa, fmaf(yc3, we, od2[w * 5 + 3]));
                    od2[w * 5 + 4] = fmaf(x4, wa, fmaf(yc4, we, od2[w * 5 + 4]));
                }
            }
        }
        segscan36(b, dist);
        emit(72);
    }
}

// ============ fallback: R1 atomic kernel (verified) ============
__global__ __launch_bounds__(TPB) void eqconv_edge_kernel_atomic(
    const float* __restrict__ f_in,
    const int*   __restrict__ eidx,
    const float* __restrict__ pos,
    const float* __restrict__ W1s_g, const float* __restrict__ W2s_g,
    const float* __restrict__ W1p_g, const float* __restrict__ W2p_g,
    const float* __restrict__ W1d_g, const float* __restrict__ W2d_g,
    float* __restrict__ out,
    int E, float snorm)
{
    __shared__ __align__(16) float smem[11264];
    float* tW1s = smem;
    float* tW1p = smem + 768;
    float* tW1d = smem + 1536;
    float* sW2s = smem + 2304;
    float* sW2p = smem + 3072;
    float* sW2d = smem + 6144;

    const int tid = threadIdx.x;
    const float base = 0.05590169943749474f * snorm;

    for (int idx = tid; idx < 768; idx += TPB) {
        int j = idx / 12, i = idx - j * 12;
        tW1s[idx] = (i < 10) ? W1s_g[i * 64 + j] : 0.f;
        tW1p[idx] = (i < 10) ? W1p_g[i * 64 + j] : 0.f;
        tW1d[idx] = (i < 10) ? W1d_g[i * 64 + j] : 0.f;
    }
    for (int idx = tid; idx < 768; idx += TPB)
        sW2s[idx] = W2s_g[idx] * base;
    for (int idx = tid; idx < 3072; idx += TPB) {
        int m = idx % 48;
        float k = (m < 12) ? 0.40824829046386307f
                : (m < 24) ? 0.33333333333333333f
                : (m < 36) ? 1.29099444873580560f
                           : 0.70710678118654752f;
        sW2p[idx] = W2p_g[idx] * (base * k);
    }
    for (int idx = tid; idx < 5120; idx += TPB) {
        int m = idx % 80;
        float k = (m < 20) ? 0.31622776601683794f
                : (m < 40) ? 0.77459666924148340f
                : (m < 60) ? 0.2f
                           : 0.70710678118654752f;
        sW2d[idx] = W2d_g[idx] * (base * k);
    }
    __syncthreads();

    int e = blockIdx.x * TPB + tid;
    if (e >= E) return;

    const int row = eidx[e];
    const int col = eidx[E + e];

    float ex = pos[row * 3 + 0] - pos[col * 3 + 0];
    float ey = pos[row * 3 + 1] - pos[col * 3 + 1];
    float ez = pos[row * 3 + 2] - pos[col * 3 + 2];
    float r = sqrtf(ex * ex + ey * ey + ez * ez + 1e-12f);
    float rinv = 1.0f / r;
    float x = ex * rinv, y = ey * rinv, z = ez * rinv;

    float sh1 = 1.7320508075688772f * x;
    float sh2 = 1.7320508075688772f * y;
    float sh3 = 1.7320508075688772f * z;
    float sh4 = 3.8729833462074170f * x * z;
    float sh5 = 3.8729833462074170f * x * y;
    float sh6 = 1.1180339887498949f * (2.f * y * y - x * x - z * z);
    float sh7 = 3.8729833462074170f * y * z;
    float sh8 = 1.9364916731037085f * (z * z - x * x);

    float emb[12];
    {
        const float F = (float)(1.14136 * 7.38905609893065 * 3.1622776601683795);
        const float inv_step = 2.2f;
#pragma unroll
        for (int i = 0; i < 10; ++i) {
            float v = (float)(i + 1) * (5.0f / 11.0f);
            float d = (r - v) * inv_step;
            float d2 = d * d;
            emb[i] = (d2 < 1.0f) ? F * expf(-2.0f / (1.0f - d2)) : 0.f;
        }
        emb[10] = 0.f; emb[11] = 0.f;
    }

    const float* fr = f_in + (size_t)row * 162;
    float* o = out + (size_t)col * 108;

    {
        float ws[12];
        fc_eval<12>(tW1s, sW2s, emb, ws);
        float2 v0 = *(const float2*)(fr);
        float X = v0.x + v0.y;
#pragma unroll
        for (int w = 0; w < 4; ++w) {
            atomAddF(o + w, X * ws[w]);
            float t1 = X * ws[4 + w];
            atomAddF(o + 4 + w * 3 + 0, t1 * sh1);
            atomAddF(o + 4 + w * 3 + 1, t1 * sh2);
            atomAddF(o + 4 + w * 3 + 2, t1 * sh3);
            float t2 = X * ws[8 + w];
            atomAddF(o + 16 + w * 5 + 0, t2 * sh4);
            atomAddF(o + 16 + w * 5 + 1, t2 * sh5);
            atomAddF(o + 16 + w * 5 + 2, t2 * sh6);
            atomAddF(o + 16 + w * 5 + 3, t2 * sh7);
            atomAddF(o + 16 + w * 5 + 4, t2 * sh8);
        }
    }
    {
        float wp[48];
        fc_eval<48>(tW1p, sW2p, emb, wp);
        float op0[4] = {0.f,0.f,0.f,0.f};
        float op1[12], op2[20];
#pragma unroll
        for (int t = 0; t < 12; ++t) op1[t] = 0.f;
#pragma unroll
        for (int t = 0; t < 20; ++t) op2[t] = 0.f;
#pragma unroll
        for (int u = 0; u < 3; ++u) {
            float2 a0 = *(const float2*)(fr + ((1 + u) * 9 + 1) * 2);
            float2 a1 = *(const float2*)(fr + ((1 + u) * 9 + 2) * 2);
            float2 a2 = *(const float2*)(fr + ((1 + u) * 9 + 3) * 2);
            float x0 = a0.x + a0.y, x1 = a1.x + a1.y, x2 = a2.x + a2.y;
            float dot = x0 * sh1 + x1 * sh2 + x2 * sh3;
            float ya0 = R10 * (x0 * sh3 + x2 * sh1);
            float ya1 = R10 * (x0 * sh2 + x1 * sh1);
            float ya2 = R30 * (2.f * x1 * sh2 - x0 * sh1 - x2 * sh3);
            float ya3 = R10 * (x1 * sh3 + x2 * sh2);
            float ya4 = R10 * (x2 * sh3 - x0 * sh1);
            float yb0 = R10 * (x2 * sh4 + x1 * sh5 - x0 * sh8) - R30 * x0 * sh6;
            float yb1 = R10 * (x0 * sh5 + x2 * sh7) + R30x2 * x1 * sh6;
            float yb2 = R10 * (x0 * sh4 + x1 * sh7 + x2 * sh8) - R30 * x2 * sh6;
#pragma unroll
            for (int w = 0; w < 4; ++w) {
                float wa = wp[u * 4 + w];
                float wb = wp[12 + u * 4 + w];
                float wc = wp[24 + u * 4 + w];
                float wd2 = wp[36 + u * 4 + w];
                op0[w] = fmaf(dot, wb, op0[w]);
                op1[w * 3 + 0] = fmaf(x0, wa, fmaf(yb0, wd2, op1[w * 3 + 0]));
                op1[w * 3 + 1] = fmaf(x1, wa, fmaf(yb1, wd2, op1[w * 3 + 1]));
                op1[w * 3 + 2] = fmaf(x2, wa, fmaf(yb2, wd2, op1[w * 3 + 2]));
                op2[w * 5 + 0] = fmaf(ya0, wc, op2[w * 5 + 0]);
                op2[w * 5 + 1] = fmaf(ya1, wc, op2[w * 5 + 1]);
                op2[w * 5 + 2] = fmaf(ya2, wc, op2[w * 5 + 2]);
                op2[w * 5 + 3] = fmaf(ya3, wc, op2[w * 5 + 3]);
                op2[w * 5 + 4] = fmaf(ya4, wc, op2[w * 5 + 4]);
            }
        }
#pragma unroll
        for (int w = 0; w < 4; ++w) atomAddF(o + 36 + w, op0[w]);
#pragma unroll
        for (int t = 0; t < 12; ++t) atomAddF(o + 40 + t, op1[t]);
#pragma unroll
        for (int t = 0; t < 20; ++t) atomAddF(o + 52 + t, op2[t]);
    }
    {
        float wd[80];
        fc_eval<80>(tW1d, sW2d, emb, wd);
        float od0[4] = {0.f,0.f,0.f,0.f};
        float od1[12], od2[20];
#pragma unroll
        for (int t = 0; t < 12; ++t) od1[t] = 0.f;
#pragma unroll
        for (int t = 0; t < 20; ++t) od2[t] = 0.f;
#pragma unroll
        for (int u = 0; u < 5; ++u) {
            float2 b0 = *(const float2*)(fr + ((4 + u) * 9 + 4) * 2);
            float2 b1 = *(const float2*)(fr + ((4 + u) * 9 + 5) * 2);
            float2 b2 = *(const float2*)(fr + ((4 + u) * 9 + 6) * 2);
            float2 b3 = *(const float2*)(fr + ((4 + u) * 9 + 7) * 2);
            float2 b4 = *(const float2*)(fr + ((4 + u) * 9 + 8) * 2);
            float x0 = b0.x + b0.y, x1 = b1.x + b1.y, x2 = b2.x + b2.y;
            float x3 = b3.x + b3.y, x4 = b4.x + b4.y;
            float dot = x0 * sh4 + x1 * sh5 + x2 * sh6 + x3 * sh7 + x4 * sh8;
            float yb0 = R10 * (x0 * sh3 + x1 * sh2 - x4 * sh1) - R30 * x2 * sh1;
            float yb1 = R10 * (x1 * sh1 + x3 * sh3) + R30x2 * x2 * sh2;
            float yb2 = R10 * (x0 * sh1 + x3 * sh2 + x4 * sh3) - R30 * x2 * sh3;
            float yc0 = CCA * (x2 * sh4 + x0 * sh6) - CCB * (x1 * sh7 + x3 * sh5);
            float yc1 = CCB * (x1 * sh8 + x4 * sh5 - x0 * sh7 - x3 * sh4)
                      - CCC * (x1 * sh6 + x2 * sh5);
            float yc2 = CCA * (x0 * sh4 - x2 * sh6 + x4 * sh8)
                      - CCC * (x1 * sh5 + x3 * sh7);
            float yc3 = -CCB * (x0 * sh5 + x1 * sh4 + x3 * sh8 + x4 * sh7)
                      - CCC * (x2 * sh7 + x3 * sh6);
            float yc4 = CCB * (x1 * sh5 - x3 * sh7) + CCA * (x2 * sh8 + x4 * sh6);
#pragma unroll
            for (int w = 0; w < 4; ++w) {
                float wa = wd[u * 4 + w];
                float wb = wd[20 + u * 4 + w];
                float wc = wd[40 + u * 4 + w];
                float we = wd[60 + u * 4 + w];
                od0[w] = fmaf(dot, wc, od0[w]);
                od1[w * 3 + 0] = fmaf(yb0, wb, od1[w * 3 + 0]);
                od1[w * 3 + 1] = fmaf(yb1, wb, od1[w * 3 + 1]);
                od1[w * 3 + 2] = fmaf(yb2, wb, od1[w * 3 + 2]);
                od2[w * 5 + 0] = fmaf(x0, wa, fmaf(yc0, we, od2[w * 5 + 0]));
                od2[w * 5 + 1] = fmaf(x1, wa, fmaf(yc1, we, od2[w * 5 + 1]));
                od2[w * 5 + 2] = fmaf(x2, wa, fmaf(yc2, we, od2[w * 5 + 2]));
                od2[w * 5 + 3] = fmaf(x3, wa, fmaf(yc3, we, od2[w * 5 + 3]));
                od2[w * 5 + 4] = fmaf(x4, wa, fmaf(yc4, we, od2[w * 5 + 4]));
            }
        }
#pragma unroll
        for (int w = 0; w < 4; ++w) atomAddF(o + 72 + w, od0[w]);
#pragma unroll
        for (int t = 0; t < 12; ++t) atomAddF(o + 76 + t, od1[t]);
#pragma unroll
        for (int t = 0; t < 20; ++t) atomAddF(o + 88 + t, od2[t]);
    }
}

extern "C" void kernel_launch(void* const* d_in, const int* in_sizes, int n_in,
                              void* d_out, int out_size, void* d_ws, size_t ws_size,
                              hipStream_t stream) {
    const float* f_in = (const float*)d_in[0];
    const int*   eidx = (const int*)d_in[1];
    const float* pos  = (const float*)d_in[2];
    const float* W1s = (const float*)d_in[5];
    const float* W2s = (const float*)d_in[6];
    const float* W1p = (const float*)d_in[7];
    const float* W2p = (const float*)d_in[8];
    const float* W1d = (const float*)d_in[9];
    const float* W2d = (const float*)d_in[10];

    const int E = in_sizes[1] / 2;
    const int N = in_sizes[0] / 162;
    const float snorm = (float)(1.0 / sqrt((double)E / (double)N));
    const int eBlocks = (E + 255) / 256;
    const int numTiles = (E + TPB - 1) / TPB;

    // ws layout: edges int2[E] | cnt[N] | cursor[N] | align16 | rec[40N floats]
    const size_t edgesBytes = (size_t)E * sizeof(int2);
    const size_t intsBytes  = edgesBytes + (size_t)(2 * N) * sizeof(int);
    const size_t recOff = (intsBytes + 15) & ~((size_t)15);
    const size_t need = recOff + (size_t)N * 40 * sizeof(float);

    if (ws_size >= need) {
        int2* edges  = (int2*)d_ws;
        int*  cnt    = (int*)((char*)d_ws + edgesBytes);
        int*  cursor = cnt + N;
        float* rec   = (float*)((char*)d_ws + recOff);

        hipMemsetAsync(cnt, 0, (size_t)N * sizeof(int), stream);
        hipMemsetAsync(d_out, 0, (size_t)out_size * sizeof(float), stream);
        build_rec_kernel<<<(N + 255) / 256, 256, 0, stream>>>(f_in, pos, rec, N);
        count_kernel<<<eBlocks, 256, 0, stream>>>(eidx + E, cnt, E);
        scan_kernel<<<1, 1024, 0, stream>>>(cnt, cursor, N);
        permute_kernel<<<eBlocks, 256, 0, stream>>>(eidx, cursor, edges, E);
        int grid = numTiles < 1536 ? numTiles : 1536;
        fused_wave_kernel<<<grid, TPB, 0, stream>>>(
            rec, edges, W1s, W2s, W1p, W2p, W1d, W2d,
            (float*)d_out, E, numTiles, snorm);
    } else {
        hipMemsetAsync(d_out, 0, (size_t)out_size * sizeof(float), stream);
        eqconv_edge_kernel_atomic<<<eBlocks, TPB, 0, stream>>>(
            f_in, eidx, pos, W1s, W2s, W1p, W2p, W1d, W2d,
            (float*)d_out, E, snorm);
    }
}

// Round 5
// 666.633 us; speedup vs baseline: 1.1002x; 1.1002x over previous
//
#include <hip/hip_runtime.h>
#include <math.h>

#define TPB 256

// ---- analytic Wigner-3j constants (verified R1: absmax 0.0156) ----
#define R10   0.31622776601683794f  // 1/sqrt(10)
#define R30   0.18257418583505536f  // 1/sqrt(30)
#define R30x2 0.36514837167011072f  // 2/sqrt(30)
#define C222_SIGN (1.0f)            // verified R1
#define CCA (C222_SIGN * 0.23904572186687872f) // 2/sqrt(70)
#define CCB (C222_SIGN * 0.20701966780270623f) // sqrt(3/70)
#define CCC (C222_SIGN * 0.11952286093343936f) // 1/sqrt(70)

__device__ __forceinline__ void atomAddF(float* p, float v) {
    __hip_atomic_fetch_add(p, v, __ATOMIC_RELAXED, __HIP_MEMORY_SCOPE_AGENT);
}

// FC with 2-nonzero radial basis: t_j = relu(ea*W1[a][j] + eb*W1[a+1][j]).
// ra points at LDS row a (stride 68, 16B-aligned: 68*4=272=17*16).
// w2g is GLOBAL pre-scaled W2 [64][M] read with wave-uniform addresses -> s_load.
template<int M>
__device__ __forceinline__ void fc2(const float* ra,
                                    const float* __restrict__ w2g,
                                    float ea, float eb, float* acc)
{
#pragma unroll
    for (int m = 0; m < M; ++m) acc[m] = 0.f;
    const float* rb = ra + 68;
#pragma unroll 2
    for (int j4 = 0; j4 < 16; ++j4) {
        float4 A  = *(const float4*)(ra + j4 * 4);
        float4 Bv = *(const float4*)(rb + j4 * 4);
        float t[4];
        t[0] = fmaxf(fmaf(eb, Bv.x, ea * A.x), 0.f);
        t[1] = fmaxf(fmaf(eb, Bv.y, ea * A.y), 0.f);
        t[2] = fmaxf(fmaf(eb, Bv.z, ea * A.z), 0.f);
        t[3] = fmaxf(fmaf(eb, Bv.w, ea * A.w), 0.f);
#pragma unroll
        for (int k = 0; k < 4; ++k) {
            const float4* w2 = (const float4*)(w2g + (size_t)(j4 * 4 + k) * M);
#pragma unroll
            for (int q = 0; q < M / 4; ++q) {
                float4 w = w2[q];
                acc[4*q+0] = fmaf(t[k], w.x, acc[4*q+0]);
                acc[4*q+1] = fmaf(t[k], w.y, acc[4*q+1]);
                acc[4*q+2] = fmaf(t[k], w.z, acc[4*q+2]);
                acc[4*q+3] = fmaf(t[k], w.w, acc[4*q+3]);
            }
        }
    }
}

// 6-step segmented inclusive scan over 36 regs; fmaf-masked (1 VALU/step/val).
__device__ __forceinline__ void segscan36(float* b, int dist) {
#pragma unroll
    for (int s = 1; s < 64; s <<= 1) {
        float msk = (dist >= s) ? 1.f : 0.f;
#pragma unroll
        for (int j = 0; j < 36; ++j) {
            float t = __shfl_up(b[j], s);
            b[j] = fmaf(msk, t, b[j]);
        }
    }
}

// ============ node-record precompute, stride 44:
// [0..2]=pos [3]=xs [4..12]=xp [16..40]=xd (pads unused) ============
__global__ __launch_bounds__(256) void build_rec_kernel(const float* __restrict__ f_in,
                                                        const float* __restrict__ pos,
                                                        float* __restrict__ rec, int N) {
    int n = blockIdx.x * 256 + threadIdx.x;
    if (n >= N) return;
    const float* f = f_in + (size_t)n * 162;
    float* r = rec + (size_t)n * 44;
    r[0] = pos[n * 3 + 0]; r[1] = pos[n * 3 + 1]; r[2] = pos[n * 3 + 2];
    float2 v0 = *(const float2*)f;
    r[3] = v0.x + v0.y;
#pragma unroll
    for (int u = 0; u < 3; ++u)
#pragma unroll
        for (int v = 0; v < 3; ++v) {
            float2 a = *(const float2*)(f + ((1 + u) * 9 + (1 + v)) * 2);
            r[4 + u * 3 + v] = a.x + a.y;
        }
    r[13] = 0.f; r[14] = 0.f; r[15] = 0.f;
#pragma unroll
    for (int u = 0; u < 5; ++u)
#pragma unroll
        for (int v = 0; v < 5; ++v) {
            float2 a = *(const float2*)(f + ((4 + u) * 9 + (4 + v)) * 2);
            r[16 + u * 5 + v] = a.x + a.y;
        }
    r[41] = 0.f; r[42] = 0.f; r[43] = 0.f;
}

// ============ pre-scale W2 into workspace: [S 64x12][P 64x48][D 64x80] ============
__global__ __launch_bounds__(256) void prep_w2_kernel(const float* __restrict__ W2s,
                                                      const float* __restrict__ W2p,
                                                      const float* __restrict__ W2d,
                                                      float* __restrict__ W2pre, float base) {
    int i = blockIdx.x * 256 + threadIdx.x;
    if (i < 768) {
        W2pre[i] = W2s[i] * base;
    } else if (i < 768 + 3072) {
        int idx = i - 768, m = idx % 48;
        float k = (m < 12) ? 0.40824829046386307f
                : (m < 24) ? 0.33333333333333333f
                : (m < 36) ? 1.29099444873580560f
                           : 0.70710678118654752f;
        W2pre[i] = W2p[idx] * (base * k);
    } else if (i < 768 + 3072 + 5120) {
        int idx = i - 3840, m = idx % 80;
        float k = (m < 20) ? 0.31622776601683794f
                : (m < 40) ? 0.77459666924148340f
                : (m < 60) ? 0.2f
                           : 0.70710678118654752f;
        W2pre[i] = W2d[idx] * (base * k);
    }
}

// ============ histogram of col ============
__global__ __launch_bounds__(256) void count_kernel(const int* __restrict__ col,
                                                    int* __restrict__ cnt, int E) {
    int e = blockIdx.x * 256 + threadIdx.x;
    if (e < E) atomicAdd(&cnt[col[e]], 1);
}

// ============ exclusive scan -> cursor (1 block, shuffle-based) ============
__global__ __launch_bounds__(1024) void scan_kernel(const int* __restrict__ cnt,
                                                    int* __restrict__ cursor, int N) {
    __shared__ int wsum[16];
    const int tid = threadIdx.x;
    const int lane = tid & 63;
    const int wv = tid >> 6;
    int carry = 0;
    for (int base = 0; base < N; base += 4096) {
        int i0 = base + tid * 4;
        int v0 = (i0 + 0 < N) ? cnt[i0 + 0] : 0;
        int v1 = (i0 + 1 < N) ? cnt[i0 + 1] : 0;
        int v2 = (i0 + 2 < N) ? cnt[i0 + 2] : 0;
        int v3 = (i0 + 3 < N) ? cnt[i0 + 3] : 0;
        int s = v0 + v1 + v2 + v3;
        int sc = s;
        for (int d = 1; d < 64; d <<= 1) {
            int t = __shfl_up(sc, d);
            if (lane >= d) sc += t;
        }
        if (lane == 63) wsum[wv] = sc;
        __syncthreads();
        int woff = carry, tot = carry;
#pragma unroll
        for (int w = 0; w < 16; ++w) {
            int x = wsum[w];
            if (w < wv) woff += x;
            tot += x;
        }
        int excl = woff + (sc - s);
        if (i0 + 0 < N) cursor[i0 + 0] = excl;
        excl += v0;
        if (i0 + 1 < N) cursor[i0 + 1] = excl;
        excl += v1;
        if (i0 + 2 < N) cursor[i0 + 2] = excl;
        excl += v2;
        if (i0 + 3 < N) cursor[i0 + 3] = excl;
        carry = tot;
        __syncthreads();
    }
}

// ============ permute edges into sorted-by-col order ============
__global__ __launch_bounds__(256) void permute_kernel(const int* __restrict__ eidx,
                                                      int* __restrict__ cursor,
                                                      int2* __restrict__ edges, int E) {
    int e = blockIdx.x * 256 + threadIdx.x;
    if (e < E) {
        int c = eidx[E + e];
        int p = atomicAdd(&cursor[c], 1);
        edges[p] = make_int2(eidx[e], c);
    }
}

// ============ fused: per-edge compute + wave-local segmented reduce ============
__global__ __launch_bounds__(TPB, 2) void fused2_kernel(
    const float* __restrict__ rec,
    const int2*  __restrict__ edges,
    const float* __restrict__ W1s_g,
    const float* __restrict__ W1p_g,
    const float* __restrict__ W1d_g,
    const float* __restrict__ W2pre,
    float* __restrict__ out,
    int E, int numTiles)
{
    __shared__ __align__(16) float sW1[2040];  // 3 paths x [10][68]

    const int tid = threadIdx.x;
    const int lane = tid & 63;

    // stage W1 (unscaled, natural [10][64] layout -> [10][68] padded)
    for (int idx = tid; idx < 1920; idx += TPB) {
        int path = idx / 640, rem = idx - path * 640;
        int i = rem >> 6, j = rem & 63;
        const float* Wg = (path == 0) ? W1s_g : (path == 1) ? W1p_g : W1d_g;
        sW1[path * 680 + i * 68 + j] = Wg[rem];
    }
    __syncthreads();

    for (int tile = blockIdx.x; tile < numTiles; tile += gridDim.x) {
        const int p = tile * TPB + tid;
        const bool valid = p < E;
        int2 ed = valid ? edges[p] : make_int2(0, 0x7fffffff);
        const int row = ed.x;
        const int col = ed.y;
        const int colIdx = valid ? col : 0;

        // ---- wave-local segmentation ----
        int prevCol = __shfl_up(col, 1);
        bool head = (lane == 0) || (col != prevCol);
        unsigned long long m = __ballot(head);
        unsigned long long below = m & ((2ull << lane) - 1ull);
        const int hd = 63 - __builtin_clzll(below);
        const bool tail = (lane == 63) ? true : (((m >> (lane + 1)) & 1ull) != 0);
        const int dist = lane - hd;

        int clf = 0, crf = 0;
        if (lane == 0 && valid && p > 0)        clf = (edges[p - 1].y == col);
        if (lane == 63 && valid && (p + 1) < E) crf = (edges[p + 1].y == col);
        const int contL = __shfl(clf, 0);
        const int contR = __shfl(crf, 63);
        const bool partial = (hd == 0 && contL) || (lane == 63 && contR);
        const bool doWrite = tail && valid;

        // ---- geometry ----
        const float* rr = rec + (size_t)row * 44;
        const float fm = valid ? 1.f : 0.f;
        float4 h0 = *(const float4*)(rr);                              // pos + xs
        float4 qc = *(const float4*)(rec + (size_t)colIdx * 44);

        float ex = h0.x - qc.x, ey = h0.y - qc.y, ez = h0.z - qc.z;
        float r = sqrtf(ex * ex + ey * ey + ez * ez + 1e-12f);
        float rinv = 1.0f / r;
        float x = ex * rinv, y = ey * rinv, z = ez * rinv;

        float sh1 = 1.7320508075688772f * x;
        float sh2 = 1.7320508075688772f * y;
        float sh3 = 1.7320508075688772f * z;
        float sh4 = 3.8729833462074170f * x * z;
        float sh5 = 3.8729833462074170f * x * y;
        float sh6 = 1.1180339887498949f * (2.f * y * y - x * x - z * z);
        float sh7 = 3.8729833462074170f * y * z;
        float sh8 = 1.9364916731037085f * (z * z - x * x);

        // ---- 2-nonzero radial basis: rows ac, ac+1 of W1 ----
        const float F = (float)(1.14136 * 7.38905609893065 * 3.1622776601683795);
        float q = r * 2.2f;                       // r/step, step = 5/11
        int a0 = (int)floorf(q) - 1;              // 0-indexed first candidate row
        int ac = min(max(a0, 0), 8);
        float d0 = q - (float)(ac + 1);
        float d0s = d0 * d0;
        float ea = (d0s < 1.f) ? F * expf(-2.f / (1.f - d0s)) : 0.f;
        float d1 = d0 - 1.f;
        float d1s = d1 * d1;
        float eb = (d1s < 1.f) ? F * expf(-2.f / (1.f - d1s)) : 0.f;

        float b[36] __attribute__((aligned(16)));

        auto emit = [&](int obase) {
            if (doWrite) {
                float* o = out + (size_t)col * 108 + obase;
                if (partial) {
#pragma unroll
                    for (int j = 0; j < 36; ++j) atomAddF(o + j, b[j]);
                } else {
#pragma unroll
                    for (int qq = 0; qq < 9; ++qq) ((float4*)o)[qq] = ((const float4*)b)[qq];
                }
            }
        };

        // ================= S path (out 0..35) =================
        {
            float ws[12];
            fc2<12>(sW1 + ac * 68, W2pre, ea, eb, ws);
            float X = h0.w * fm;
#pragma unroll
            for (int w = 0; w < 4; ++w) {
                b[w] = X * ws[w];
                float t1 = X * ws[4 + w];
                b[4 + w * 3 + 0] = t1 * sh1;
                b[4 + w * 3 + 1] = t1 * sh2;
                b[4 + w * 3 + 2] = t1 * sh3;
                float t2 = X * ws[8 + w];
                b[16 + w * 5 + 0] = t2 * sh4;
                b[16 + w * 5 + 1] = t2 * sh5;
                b[16 + w * 5 + 2] = t2 * sh6;
                b[16 + w * 5 + 3] = t2 * sh7;
                b[16 + w * 5 + 4] = t2 * sh8;
            }
        }
        segscan36(b, dist);
        emit(0);

        // ================= P path (out 36..71) =================
        {
            float wp[48];
            fc2<48>(sW1 + 680 + ac * 68, W2pre + 768, ea, eb, wp);
            float xp[12];
#pragma unroll
            for (int i = 0; i < 3; ++i) ((float4*)xp)[i] = ((const float4*)(rr + 4))[i];
            float* op0 = b;       // 4
            float* op1 = b + 4;   // 12
            float* op2 = b + 16;  // 20
#pragma unroll
            for (int t = 0; t < 36; ++t) b[t] = 0.f;
#pragma unroll
            for (int u = 0; u < 3; ++u) {
                float x0 = xp[u*3+0] * fm, x1 = xp[u*3+1] * fm, x2 = xp[u*3+2] * fm;
                float dot = x0 * sh1 + x1 * sh2 + x2 * sh3;
                float ya0 = R10 * (x0 * sh3 + x2 * sh1);
                float ya1 = R10 * (x0 * sh2 + x1 * sh1);
                float ya2 = R30 * (2.f * x1 * sh2 - x0 * sh1 - x2 * sh3);
                float ya3 = R10 * (x1 * sh3 + x2 * sh2);
                float ya4 = R10 * (x2 * sh3 - x0 * sh1);
                float yb0 = R10 * (x2 * sh4 + x1 * sh5 - x0 * sh8) - R30 * x0 * sh6;
                float yb1 = R10 * (x0 * sh5 + x2 * sh7) + R30x2 * x1 * sh6;
                float yb2 = R10 * (x0 * sh4 + x1 * sh7 + x2 * sh8) - R30 * x2 * sh6;
#pragma unroll
                for (int w = 0; w < 4; ++w) {
                    float wa = wp[u * 4 + w];
                    float wb = wp[12 + u * 4 + w];
                    float wc = wp[24 + u * 4 + w];
                    float wd2 = wp[36 + u * 4 + w];
                    op0[w] = fmaf(dot, wb, op0[w]);
                    op1[w * 3 + 0] = fmaf(x0, wa, fmaf(yb0, wd2, op1[w * 3 + 0]));
                    op1[w * 3 + 1] = fmaf(x1, wa, fmaf(yb1, wd2, op1[w * 3 + 1]));
                    op1[w * 3 + 2] = fmaf(x2, wa, fmaf(yb2, wd2, op1[w * 3 + 2]));
                    op2[w * 5 + 0] = fmaf(ya0, wc, op2[w * 5 + 0]);
                    op2[w * 5 + 1] = fmaf(ya1, wc, op2[w * 5 + 1]);
                    op2[w * 5 + 2] = fmaf(ya2, wc, op2[w * 5 + 2]);
                    op2[w * 5 + 3] = fmaf(ya3, wc, op2[w * 5 + 3]);
                    op2[w * 5 + 4] = fmaf(ya4, wc, op2[w * 5 + 4]);
                }
            }
        }
        segscan36(b, dist);
        emit(36);

        // ================= D path (out 72..107) =================
        {
            float wd[80];
            fc2<80>(sW1 + 1360 + ac * 68, W2pre + 3840, ea, eb, wd);
            float xd[28];
#pragma unroll
            for (int i = 0; i < 7; ++i) ((float4*)xd)[i] = ((const float4*)(rr + 16))[i];
            float* od0 = b;       // 4
            float* od1 = b + 4;   // 12
            float* od2 = b + 16;  // 20
#pragma unroll
            for (int t = 0; t < 36; ++t) b[t] = 0.f;
#pragma unroll
            for (int u = 0; u < 5; ++u) {
                float x0 = xd[u*5+0] * fm, x1 = xd[u*5+1] * fm, x2 = xd[u*5+2] * fm;
                float x3 = xd[u*5+3] * fm, x4 = xd[u*5+4] * fm;
                float dot = x0 * sh4 + x1 * sh5 + x2 * sh6 + x3 * sh7 + x4 * sh8;
                float yb0 = R10 * (x0 * sh3 + x1 * sh2 - x4 * sh1) - R30 * x2 * sh1;
                float yb1 = R10 * (x1 * sh1 + x3 * sh3) + R30x2 * x2 * sh2;
                float yb2 = R10 * (x0 * sh1 + x3 * sh2 + x4 * sh3) - R30 * x2 * sh3;
                float yc0 = CCA * (x2 * sh4 + x0 * sh6) - CCB * (x1 * sh7 + x3 * sh5);
                float yc1 = CCB * (x1 * sh8 + x4 * sh5 - x0 * sh7 - x3 * sh4)
                          - CCC * (x1 * sh6 + x2 * sh5);
                float yc2 = CCA * (x0 * sh4 - x2 * sh6 + x4 * sh8)
                          - CCC * (x1 * sh5 + x3 * sh7);
                float yc3 = -CCB * (x0 * sh5 + x1 * sh4 + x3 * sh8 + x4 * sh7)
                          - CCC * (x2 * sh7 + x3 * sh6);
                float yc4 = CCB * (x1 * sh5 - x3 * sh7) + CCA * (x2 * sh8 + x4 * sh6);
#pragma unroll
                for (int w = 0; w < 4; ++w) {
                    float wa = wd[u * 4 + w];
                    float wb = wd[20 + u * 4 + w];
                    float wc = wd[40 + u * 4 + w];
                    float we = wd[60 + u * 4 + w];
                    od0[w] = fmaf(dot, wc, od0[w]);
                    od1[w * 3 + 0] = fmaf(yb0, wb, od1[w * 3 + 0]);
                    od1[w * 3 + 1] = fmaf(yb1, wb, od1[w * 3 + 1]);
                    od1[w * 3 + 2] = fmaf(yb2, wb, od1[w * 3 + 2]);
                    od2[w * 5 + 0] = fmaf(x0, wa, fmaf(yc0, we, od2[w * 5 + 0]));
                    od2[w * 5 + 1] = fmaf(x1, wa, fmaf(yc1, we, od2[w * 5 + 1]));
                    od2[w * 5 + 2] = fmaf(x2, wa, fmaf(yc2, we, od2[w * 5 + 2]));
                    od2[w * 5 + 3] = fmaf(x3, wa, fmaf(yc3, we, od2[w * 5 + 3]));
                    od2[w * 5 + 4] = fmaf(x4, wa, fmaf(yc4, we, od2[w * 5 + 4]));
                }
            }
        }
        segscan36(b, dist);
        emit(72);
    }
}

// ============ fallback: R1 atomic kernel (verified; no workspace needed) ============
template<int M>
__device__ __forceinline__ void fc_eval(const float* sW1T, const float* sW2,
                                        const float emb[12], float* acc)
{
#pragma unroll
    for (int m = 0; m < M; ++m) acc[m] = 0.f;
#pragma unroll 2
    for (int j = 0; j < 64; ++j) {
        const float4* w1r = (const float4*)(sW1T + j * 12);
        float4 A = w1r[0], B = w1r[1], C = w1r[2];
        float t = A.x*emb[0] + A.y*emb[1] + A.z*emb[2] + A.w*emb[3]
                + B.x*emb[4] + B.y*emb[5] + B.z*emb[6] + B.w*emb[7]
                + C.x*emb[8] + C.y*emb[9];
        t = fmaxf(t, 0.f);
        const float4* w2r = (const float4*)(sW2 + j * M);
#pragma unroll
        for (int q = 0; q < M / 4; ++q) {
            float4 V = w2r[q];
            acc[4*q+0] = fmaf(t, V.x, acc[4*q+0]);
            acc[4*q+1] = fmaf(t, V.y, acc[4*q+1]);
            acc[4*q+2] = fmaf(t, V.z, acc[4*q+2]);
            acc[4*q+3] = fmaf(t, V.w, acc[4*q+3]);
        }
    }
}

__global__ __launch_bounds__(TPB) void eqconv_edge_kernel_atomic(
    const float* __restrict__ f_in,
    const int*   __restrict__ eidx,
    const float* __restrict__ pos,
    const float* __restrict__ W1s_g, const float* __restrict__ W2s_g,
    const float* __restrict__ W1p_g, const float* __restrict__ W2p_g,
    const float* __restrict__ W1d_g, const float* __restrict__ W2d_g,
    float* __restrict__ out,
    int E, float snorm)
{
    __shared__ __align__(16) float smem[11264];
    float* tW1s = smem;
    float* tW1p = smem + 768;
    float* tW1d = smem + 1536;
    float* sW2s = smem + 2304;
    float* sW2p = smem + 3072;
    float* sW2d = smem + 6144;

    const int tid = threadIdx.x;
    const float base = 0.05590169943749474f * snorm;

    for (int idx = tid; idx < 768; idx += TPB) {
        int j = idx / 12, i = idx - j * 12;
        tW1s[idx] = (i < 10) ? W1s_g[i * 64 + j] : 0.f;
        tW1p[idx] = (i < 10) ? W1p_g[i * 64 + j] : 0.f;
        tW1d[idx] = (i < 10) ? W1d_g[i * 64 + j] : 0.f;
    }
    for (int idx = tid; idx < 768; idx += TPB)
        sW2s[idx] = W2s_g[idx] * base;
    for (int idx = tid; idx < 3072; idx += TPB) {
        int m = idx % 48;
        float k = (m < 12) ? 0.40824829046386307f
                : (m < 24) ? 0.33333333333333333f
                : (m < 36) ? 1.29099444873580560f
                           : 0.70710678118654752f;
        sW2p[idx] = W2p_g[idx] * (base * k);
    }
    for (int idx = tid; idx < 5120; idx += TPB) {
        int m = idx % 80;
        float k = (m < 20) ? 0.31622776601683794f
                : (m < 40) ? 0.77459666924148340f
                : (m < 60) ? 0.2f
                           : 0.70710678118654752f;
        sW2d[idx] = W2d_g[idx] * (base * k);
    }
    __syncthreads();

    int e = blockIdx.x * TPB + tid;
    if (e >= E) return;

    const int row = eidx[e];
    const int col = eidx[E + e];

    float ex = pos[row * 3 + 0] - pos[col * 3 + 0];
    float ey = pos[row * 3 + 1] - pos[col * 3 + 1];
    float ez = pos[row * 3 + 2] - pos[col * 3 + 2];
    float r = sqrtf(ex * ex + ey * ey + ez * ez + 1e-12f);
    float rinv = 1.0f / r;
    float x = ex * rinv, y = ey * rinv, z = ez * rinv;

    float sh1 = 1.7320508075688772f * x;
    float sh2 = 1.7320508075688772f * y;
    float sh3 = 1.7320508075688772f * z;
    float sh4 = 3.8729833462074170f * x * z;
    float sh5 = 3.8729833462074170f * x * y;
    float sh6 = 1.1180339887498949f * (2.f * y * y - x * x - z * z);
    float sh7 = 3.8729833462074170f * y * z;
    float sh8 = 1.9364916731037085f * (z * z - x * x);

    float emb[12];
    {
        const float F = (float)(1.14136 * 7.38905609893065 * 3.1622776601683795);
        const float inv_step = 2.2f;
#pragma unroll
        for (int i = 0; i < 10; ++i) {
            float v = (float)(i + 1) * (5.0f / 11.0f);
            float d = (r - v) * inv_step;
            float d2 = d * d;
            emb[i] = (d2 < 1.0f) ? F * expf(-2.0f / (1.0f - d2)) : 0.f;
        }
        emb[10] = 0.f; emb[11] = 0.f;
    }

    const float* fr = f_in + (size_t)row * 162;
    float* o = out + (size_t)col * 108;

    {
        float ws[12];
        fc_eval<12>(tW1s, sW2s, emb, ws);
        float2 v0 = *(const float2*)(fr);
        float X = v0.x + v0.y;
#pragma unroll
        for (int w = 0; w < 4; ++w) {
            atomAddF(o + w, X * ws[w]);
            float t1 = X * ws[4 + w];
            atomAddF(o + 4 + w * 3 + 0, t1 * sh1);
            atomAddF(o + 4 + w * 3 + 1, t1 * sh2);
            atomAddF(o + 4 + w * 3 + 2, t1 * sh3);
            float t2 = X * ws[8 + w];
            atomAddF(o + 16 + w * 5 + 0, t2 * sh4);
            atomAddF(o + 16 + w * 5 + 1, t2 * sh5);
            atomAddF(o + 16 + w * 5 + 2, t2 * sh6);
            atomAddF(o + 16 + w * 5 + 3, t2 * sh7);
            atomAddF(o + 16 + w * 5 + 4, t2 * sh8);
        }
    }
    {
        float wp[48];
        fc_eval<48>(tW1p, sW2p, emb, wp);
        float op0[4] = {0.f,0.f,0.f,0.f};
        float op1[12], op2[20];
#pragma unroll
        for (int t = 0; t < 12; ++t) op1[t] = 0.f;
#pragma unroll
        for (int t = 0; t < 20; ++t) op2[t] = 0.f;
#pragma unroll
        for (int u = 0; u < 3; ++u) {
            float2 a0 = *(const float2*)(fr + ((1 + u) * 9 + 1) * 2);
            float2 a1 = *(const float2*)(fr + ((1 + u) * 9 + 2) * 2);
            float2 a2 = *(const float2*)(fr + ((1 + u) * 9 + 3) * 2);
            float x0 = a0.x + a0.y, x1 = a1.x + a1.y, x2 = a2.x + a2.y;
            float dot = x0 * sh1 + x1 * sh2 + x2 * sh3;
            float ya0 = R10 * (x0 * sh3 + x2 * sh1);
            float ya1 = R10 * (x0 * sh2 + x1 * sh1);
            float ya2 = R30 * (2.f * x1 * sh2 - x0 * sh1 - x2 * sh3);
            float ya3 = R10 * (x1 * sh3 + x2 * sh2);
            float ya4 = R10 * (x2 * sh3 - x0 * sh1);
            float yb0 = R10 * (x2 * sh4 + x1 * sh5 - x0 * sh8) - R30 * x0 * sh6;
            float yb1 = R10 * (x0 * sh5 + x2 * sh7) + R30x2 * x1 * sh6;
            float yb2 = R10 * (x0 * sh4 + x1 * sh7 + x2 * sh8) - R30 * x2 * sh6;
#pragma unroll
            for (int w = 0; w < 4; ++w) {
                float wa = wp[u * 4 + w];
                float wb = wp[12 + u * 4 + w];
                float wc = wp[24 + u * 4 + w];
                float wd2 = wp[36 + u * 4 + w];
                op0[w] = fmaf(dot, wb, op0[w]);
                op1[w * 3 + 0] = fmaf(x0, wa, fmaf(yb0, wd2, op1[w * 3 + 0]));
                op1[w * 3 + 1] = fmaf(x1, wa, fmaf(yb1, wd2, op1[w * 3 + 1]));
                op1[w * 3 + 2] = fmaf(x2, wa, fmaf(yb2, wd2, op1[w * 3 + 2]));
                op2[w * 5 + 0] = fmaf(ya0, wc, op2[w * 5 + 0]);
                op2[w * 5 + 1] = fmaf(ya1, wc, op2[w * 5 + 1]);
                op2[w * 5 + 2] = fmaf(ya2, wc, op2[w * 5 + 2]);
                op2[w * 5 + 3] = fmaf(ya3, wc, op2[w * 5 + 3]);
                op2[w * 5 + 4] = fmaf(ya4, wc, op2[w * 5 + 4]);
            }
        }
#pragma unroll
        for (int w = 0; w < 4; ++w) atomAddF(o + 36 + w, op0[w]);
#pragma unroll
        for (int t = 0; t < 12; ++t) atomAddF(o + 40 + t, op1[t]);
#pragma unroll
        for (int t = 0; t < 20; ++t) atomAddF(o + 52 + t, op2[t]);
    }
    {
        float wd[80];
        fc_eval<80>(tW1d, sW2d, emb, wd);
        float od0[4] = {0.f,0.f,0.f,0.f};
        float od1[12], od2[20];
#pragma unroll
        for (int t = 0; t < 12; ++t) od1[t] = 0.f;
#pragma unroll
        for (int t = 0; t < 20; ++t) od2[t] = 0.f;
#pragma unroll
        for (int u = 0; u < 5; ++u) {
            float2 b0 = *(const float2*)(fr + ((4 + u) * 9 + 4) * 2);
            float2 b1 = *(const float2*)(fr + ((4 + u) * 9 + 5) * 2);
            float2 b2 = *(const float2*)(fr + ((4 + u) * 9 + 6) * 2);
            float2 b3 = *(const float2*)(fr + ((4 + u) * 9 + 7) * 2);
            float2 b4 = *(const float2*)(fr + ((4 + u) * 9 + 8) * 2);
            float x0 = b0.x + b0.y, x1 = b1.x + b1.y, x2 = b2.x + b2.y;
            float x3 = b3.x + b3.y, x4 = b4.x + b4.y;
            float dot = x0 * sh4 + x1 * sh5 + x2 * sh6 + x3 * sh7 + x4 * sh8;
            float yb0 = R10 * (x0 * sh3 + x1 * sh2 - x4 * sh1) - R30 * x2 * sh1;
            float yb1 = R10 * (x1 * sh1 + x3 * sh3) + R30x2 * x2 * sh2;
            float yb2 = R10 * (x0 * sh1 + x3 * sh2 + x4 * sh3) - R30 * x2 * sh3;
            float yc0 = CCA * (x2 * sh4 + x0 * sh6) - CCB * (x1 * sh7 + x3 * sh5);
            float yc1 = CCB * (x1 * sh8 + x4 * sh5 - x0 * sh7 - x3 * sh4)
                      - CCC * (x1 * sh6 + x2 * sh5);
            float yc2 = CCA * (x0 * sh4 - x2 * sh6 + x4 * sh8)
                      - CCC * (x1 * sh5 + x3 * sh7);
            float yc3 = -CCB * (x0 * sh5 + x1 * sh4 + x3 * sh8 + x4 * sh7)
                      - CCC * (x2 * sh7 + x3 * sh6);
            float yc4 = CCB * (x1 * sh5 - x3 * sh7) + CCA * (x2 * sh8 + x4 * sh6);
#pragma unroll
            for (int w = 0; w < 4; ++w) {
                float wa = wd[u * 4 + w];
                float wb = wd[20 + u * 4 + w];
                float wc = wd[40 + u * 4 + w];
                float we = wd[60 + u * 4 + w];
                od0[w] = fmaf(dot, wc, od0[w]);
                od1[w * 3 + 0] = fmaf(yb0, wb, od1[w * 3 + 0]);
                od1[w * 3 + 1] = fmaf(yb1, wb, od1[w * 3 + 1]);
                od1[w * 3 + 2] = fmaf(yb2, wb, od1[w * 3 + 2]);
                od2[w * 5 + 0] = fmaf(x0, wa, fmaf(yc0, we, od2[w * 5 + 0]));
                od2[w * 5 + 1] = fmaf(x1, wa, fmaf(yc1, we, od2[w * 5 + 1]));
                od2[w * 5 + 2] = fmaf(x2, wa, fmaf(yc2, we, od2[w * 5 + 2]));
                od2[w * 5 + 3] = fmaf(x3, wa, fmaf(yc3, we, od2[w * 5 + 3]));
                od2[w * 5 + 4] = fmaf(x4, wa, fmaf(yc4, we, od2[w * 5 + 4]));
            }
        }
#pragma unroll
        for (int w = 0; w < 4; ++w) atomAddF(o + 72 + w, od0[w]);
#pragma unroll
        for (int t = 0; t < 12; ++t) atomAddF(o + 76 + t, od1[t]);
#pragma unroll
        for (int t = 0; t < 20; ++t) atomAddF(o + 88 + t, od2[t]);
    }
}

extern "C" void kernel_launch(void* const* d_in, const int* in_sizes, int n_in,
                              void* d_out, int out_size, void* d_ws, size_t ws_size,
                              hipStream_t stream) {
    const float* f_in = (const float*)d_in[0];
    const int*   eidx = (const int*)d_in[1];
    const float* pos  = (const float*)d_in[2];
    const float* W1s = (const float*)d_in[5];
    const float* W2s = (const float*)d_in[6];
    const float* W1p = (const float*)d_in[7];
    const float* W2p = (const float*)d_in[8];
    const float* W1d = (const float*)d_in[9];
    const float* W2d = (const float*)d_in[10];

    const int E = in_sizes[1] / 2;
    const int N = in_sizes[0] / 162;
    const float snorm = (float)(1.0 / sqrt((double)E / (double)N));
    const float base = 0.05590169943749474f * snorm;   // sqrt2/(8*sqrt10) * snorm
    const int eBlocks = (E + 255) / 256;
    const int numTiles = (E + TPB - 1) / TPB;

    // ws: edges int2[E] | cnt[N] | cursor[N] | pad16 | rec[44N] | pad16 | W2pre[8960]
    const size_t edgesBytes = (size_t)E * sizeof(int2);
    const size_t intsBytes  = edgesBytes + (size_t)(2 * N) * sizeof(int);
    const size_t recOff  = (intsBytes + 15) & ~((size_t)15);
    const size_t w2Off   = (recOff + (size_t)N * 44 * sizeof(float) + 15) & ~((size_t)15);
    const size_t need    = w2Off + 8960 * sizeof(float);

    if (ws_size >= need) {
        int2* edges  = (int2*)d_ws;
        int*  cnt    = (int*)((char*)d_ws + edgesBytes);
        int*  cursor = cnt + N;
        float* rec   = (float*)((char*)d_ws + recOff);
        float* W2pre = (float*)((char*)d_ws + w2Off);

        hipMemsetAsync(cnt, 0, (size_t)N * sizeof(int), stream);
        hipMemsetAsync(d_out, 0, (size_t)out_size * sizeof(float), stream);
        build_rec_kernel<<<(N + 255) / 256, 256, 0, stream>>>(f_in, pos, rec, N);
        prep_w2_kernel<<<35, 256, 0, stream>>>(W2s, W2p, W2d, W2pre, base);
        count_kernel<<<eBlocks, 256, 0, stream>>>(eidx + E, cnt, E);
        scan_kernel<<<1, 1024, 0, stream>>>(cnt, cursor, N);
        permute_kernel<<<eBlocks, 256, 0, stream>>>(eidx, cursor, edges, E);
        fused2_kernel<<<numTiles, TPB, 0, stream>>>(
            rec, edges, W1s, W1p, W1d, W2pre,
            (float*)d_out, E, numTiles);
    } else {
        hipMemsetAsync(d_out, 0, (size_t)out_size * sizeof(float), stream);
        eqconv_edge_kernel_atomic<<<eBlocks, TPB, 0, stream>>>(
            f_in, eidx, pos, W1s, W2s, W1p, W2p, W1d, W2d,
            (float*)d_out, E, snorm);
    }
}

// Round 9
// 508.380 us; speedup vs baseline: 1.4426x; 1.3113x over previous
//
#include <hip/hip_runtime.h>
#include <math.h>

#define TPB 256

// ---- analytic Wigner-3j constants (verified R1: absmax 0.0156) ----
#define R10   0.31622776601683794f  // 1/sqrt(10)
#define R30   0.18257418583505536f  // 1/sqrt(30)
#define R30x2 0.36514837167011072f  // 2/sqrt(30)
#define C222_SIGN (1.0f)            // verified R1
#define CCA (C222_SIGN * 0.23904572186687872f) // 2/sqrt(70)
#define CCB (C222_SIGN * 0.20701966780270623f) // sqrt(3/70)
#define CCC (C222_SIGN * 0.11952286093343936f) // 1/sqrt(70)

#define TROW 144   // table row stride (140 used, padded)

__device__ __forceinline__ void atomAddF(float* p, float v) {
    __hip_atomic_fetch_add(p, v, __ATOMIC_RELAXED, __HIP_MEMORY_SCOPE_AGENT);
}

// 6-step segmented inclusive scan over 36 regs (R5-verified).
__device__ __forceinline__ void segscan36(float* b, int dist) {
#pragma unroll
    for (int s = 1; s < 64; s <<= 1) {
        float msk = (dist >= s) ? 1.f : 0.f;
#pragma unroll
        for (int j = 0; j < 36; ++j) {
            float t = __shfl_up(b[j], s);
            b[j] = fmaf(msk, t, b[j]);
        }
    }
}

// ============ node records (stride 44) + col histogram into cursor ============
__global__ __launch_bounds__(256) void build_rec_count(const float* __restrict__ f_in,
                                                       const float* __restrict__ pos,
                                                       const int* __restrict__ eidx,
                                                       float* __restrict__ rec,
                                                       int* __restrict__ cnt,
                                                       int N, int E) {
    int i = blockIdx.x * 256 + threadIdx.x;
    if (i < N) {
        const float* f = f_in + (size_t)i * 162;
        float* r = rec + (size_t)i * 44;
        r[0] = pos[i * 3 + 0]; r[1] = pos[i * 3 + 1]; r[2] = pos[i * 3 + 2];
        float2 v0 = *(const float2*)f;
        r[3] = v0.x + v0.y;
#pragma unroll
        for (int u = 0; u < 3; ++u)
#pragma unroll
            for (int v = 0; v < 3; ++v) {
                float2 a = *(const float2*)(f + ((1 + u) * 9 + (1 + v)) * 2);
                r[4 + u * 3 + v] = a.x + a.y;
            }
        r[13] = 0.f; r[14] = 0.f; r[15] = 0.f;
#pragma unroll
        for (int u = 0; u < 5; ++u)
#pragma unroll
            for (int v = 0; v < 5; ++v) {
                float2 a = *(const float2*)(f + ((4 + u) * 9 + (4 + v)) * 2);
                r[16 + u * 5 + v] = a.x + a.y;
            }
        r[41] = 0.f; r[42] = 0.f; r[43] = 0.f;
    }
    if (i < E) atomicAdd(&cnt[eidx[E + i]], 1);
}

// ============ radial FC table: row bin = exact FC outputs at r = bin*Delta ============
// cols 0..11 = S (x12), 12..59 = P (x48), 60..139 = D (x80), pre-scaled by base*kf.
__global__ __launch_bounds__(256) void build_table(const float* __restrict__ W1s,
                                                   const float* __restrict__ W2s,
                                                   const float* __restrict__ W1p,
                                                   const float* __restrict__ W2p,
                                                   const float* __restrict__ W1d,
                                                   const float* __restrict__ W2d,
                                                   float* __restrict__ table,
                                                   float Delta, float base) {
    __shared__ float t3[192];
    const int tid = threadIdx.x;
    const float r = (float)blockIdx.x * Delta;

    // --- 2-nonzero radial basis (R5-verified formula) ---
    const float F = (float)(1.14136 * 7.38905609893065 * 3.1622776601683795);
    float qq = r * 2.2f;
    int a0 = (int)floorf(qq) - 1;
    int ac = min(max(a0, 0), 8);
    float d0 = qq - (float)(ac + 1);
    float d0s = d0 * d0;
    float ea = (d0s < 1.f) ? F * expf(-2.f / (1.f - d0s)) : 0.f;
    float d1 = d0 - 1.f;
    float d1s = d1 * d1;
    float eb = (d1s < 1.f) ? F * expf(-2.f / (1.f - d1s)) : 0.f;

    if (tid < 192) {
        int path = tid >> 6, j = tid & 63;
        const float* W1 = (path == 0) ? W1s : (path == 1) ? W1p : W1d;
        float u = W1[ac * 64 + j];
        float v = W1[(ac + 1) * 64 + j];
        t3[tid] = fmaxf(fmaf(eb, v, ea * u), 0.f);
    }
    __syncthreads();
    if (tid >= 140) return;

    const float* W2; const float* t; int M, m; float kf;
    if (tid < 12) {
        W2 = W2s; t = t3; M = 12; m = tid; kf = 1.f;
    } else if (tid < 60) {
        W2 = W2p; t = t3 + 64; M = 48; m = tid - 12;
        kf = (m < 12) ? 0.40824829046386307f
           : (m < 24) ? 0.33333333333333333f
           : (m < 36) ? 1.29099444873580560f
                      : 0.70710678118654752f;
    } else {
        W2 = W2d; t = t3 + 128; M = 80; m = tid - 60;
        kf = (m < 20) ? 0.31622776601683794f
           : (m < 40) ? 0.77459666924148340f
           : (m < 60) ? 0.2f
                      : 0.70710678118654752f;
    }
    float acc = 0.f;
#pragma unroll 4
    for (int j = 0; j < 64; ++j)
        acc = fmaf(t[j], W2[j * M + m], acc);
    table[(size_t)blockIdx.x * TROW + tid] = acc * (base * kf);
}

// ============ exclusive scan, IN PLACE over `data` (1 block; R5-verified core) ============
// no __restrict__: in-place aliasing is intentional (each thread reads its 4 before writing).
__global__ __launch_bounds__(1024) void scan_kernel(int* data, int N) {
    __shared__ int wsum[16];
    const int tid = threadIdx.x;
    const int lane = tid & 63;
    const int wv = tid >> 6;
    int carry = 0;
    for (int base = 0; base < N; base += 4096) {
        int i0 = base + tid * 4;
        int v0 = (i0 + 0 < N) ? data[i0 + 0] : 0;
        int v1 = (i0 + 1 < N) ? data[i0 + 1] : 0;
        int v2 = (i0 + 2 < N) ? data[i0 + 2] : 0;
        int v3 = (i0 + 3 < N) ? data[i0 + 3] : 0;
        int s = v0 + v1 + v2 + v3;
        int sc = s;
        for (int d = 1; d < 64; d <<= 1) {
            int t = __shfl_up(sc, d);
            if (lane >= d) sc += t;
        }
        if (lane == 63) wsum[wv] = sc;
        __syncthreads();
        int woff = carry, tot = carry;
#pragma unroll
        for (int w = 0; w < 16; ++w) {
            int x = wsum[w];
            if (w < wv) woff += x;
            tot += x;
        }
        int excl = woff + (sc - s);
        if (i0 + 0 < N) data[i0 + 0] = excl;
        excl += v0;
        if (i0 + 1 < N) data[i0 + 1] = excl;
        excl += v1;
        if (i0 + 2 < N) data[i0 + 2] = excl;
        excl += v2;
        if (i0 + 3 < N) data[i0 + 3] = excl;
        carry = tot;
        __syncthreads();
    }
}

// ============ permute edges into sorted-by-col order (R5-verified) ============
__global__ __launch_bounds__(256) void permute_kernel(const int* __restrict__ eidx,
                                                      int* __restrict__ cursor,
                                                      int2* __restrict__ edges, int E) {
    int e = blockIdx.x * 256 + threadIdx.x;
    if (e < E) {
        int c = eidx[E + e];
        int p = atomicAdd(&cursor[c], 1);
        edges[p] = make_int2(eidx[e], c);
    }
}

// ============ fused: table-lerp FC + per-edge TP + wave segmented reduce ============
__global__ __launch_bounds__(TPB, 2) void fused3_kernel(
    const float* __restrict__ rec,
    const int2*  __restrict__ edges,
    const float* __restrict__ table,
    float* __restrict__ out,
    int E, int NB, float invDelta)
{
    const int tid = threadIdx.x;
    const int lane = tid & 63;

    const int p = blockIdx.x * TPB + tid;
    const bool valid = p < E;
    int2 ed = valid ? edges[p] : make_int2(0, 0x7fffffff);
    const int row = ed.x;
    const int col = ed.y;
    const int colIdx = valid ? col : 0;

    // ---- wave-local segmentation (R5-verified) ----
    int prevCol = __shfl_up(col, 1);
    bool head = (lane == 0) || (col != prevCol);
    unsigned long long m = __ballot(head);
    unsigned long long below = m & ((2ull << lane) - 1ull);
    const int hd = 63 - __builtin_clzll(below);
    const bool tail = (lane == 63) ? true : (((m >> (lane + 1)) & 1ull) != 0);
    const int dist = lane - hd;
    int clf = 0, crf = 0;
    if (lane == 0 && valid && p > 0)        clf = (edges[p - 1].y == col);
    if (lane == 63 && valid && (p + 1) < E) crf = (edges[p + 1].y == col);
    const int contL = __shfl(clf, 0);
    const int contR = __shfl(crf, 63);
    const bool partial = (hd == 0 && contL) || (lane == 63 && contR);
    const bool doWrite = tail && valid;

    // ---- geometry (R5-verified) ----
    const float* rr = rec + (size_t)row * 44;
    const float fm = valid ? 1.f : 0.f;
    float4 h0 = *(const float4*)(rr);
    float4 qc = *(const float4*)(rec + (size_t)colIdx * 44);

    float ex = h0.x - qc.x, ey = h0.y - qc.y, ez = h0.z - qc.z;
    float r = sqrtf(ex * ex + ey * ey + ez * ez + 1e-12f);
    float rinv = 1.0f / r;
    float x = ex * rinv, y = ey * rinv, z = ez * rinv;

    float sh1 = 1.7320508075688772f * x;
    float sh2 = 1.7320508075688772f * y;
    float sh3 = 1.7320508075688772f * z;
    float sh4 = 3.8729833462074170f * x * z;
    float sh5 = 3.8729833462074170f * x * y;
    float sh6 = 1.1180339887498949f * (2.f * y * y - x * x - z * z);
    float sh7 = 3.8729833462074170f * y * z;
    float sh8 = 1.9364916731037085f * (z * z - x * x);

    // ---- radial table lookup: bin + lerp frac (FC==0 exactly for r>=5) ----
    float rn = r * invDelta;
    int bin = (int)floorf(rn);
    float f = rn - (float)bin;
    if (bin >= NB) { bin = NB - 1; f = 1.f; }   // table[NB] == 0 row (exact)
    const float* T0 = table + (size_t)bin * TROW;
    const float* T1 = T0 + TROW;

    float b[36] __attribute__((aligned(16)));

    auto emit = [&](int obase) {
        if (doWrite) {
            float* o = out + (size_t)col * 108 + obase;
            if (partial) {
#pragma unroll
                for (int j = 0; j < 36; ++j) atomAddF(o + j, b[j]);
            } else {
#pragma unroll
                for (int qq = 0; qq < 9; ++qq) ((float4*)o)[qq] = ((const float4*)b)[qq];
            }
        }
    };

    // ================= S path (table cols 0..11 -> out 0..35) =================
    {
        float ws[12];
#pragma unroll
        for (int q = 0; q < 3; ++q) {
            float4 a = *(const float4*)(T0 + q * 4);
            float4 c = *(const float4*)(T1 + q * 4);
            ws[q * 4 + 0] = fmaf(f, c.x - a.x, a.x);
            ws[q * 4 + 1] = fmaf(f, c.y - a.y, a.y);
            ws[q * 4 + 2] = fmaf(f, c.z - a.z, a.z);
            ws[q * 4 + 3] = fmaf(f, c.w - a.w, a.w);
        }
        float X = h0.w * fm;
#pragma unroll
        for (int w = 0; w < 4; ++w) {
            b[w] = X * ws[w];
            float t1 = X * ws[4 + w];
            b[4 + w * 3 + 0] = t1 * sh1;
            b[4 + w * 3 + 1] = t1 * sh2;
            b[4 + w * 3 + 2] = t1 * sh3;
            float t2 = X * ws[8 + w];
            b[16 + w * 5 + 0] = t2 * sh4;
            b[16 + w * 5 + 1] = t2 * sh5;
            b[16 + w * 5 + 2] = t2 * sh6;
            b[16 + w * 5 + 3] = t2 * sh7;
            b[16 + w * 5 + 4] = t2 * sh8;
        }
        segscan36(b, dist);
        emit(0);
    }

    // ================= P path (table cols 12..59 -> out 36..71) =================
    {
        float wp[48];
#pragma unroll
        for (int q = 0; q < 12; ++q) {
            float4 a = *(const float4*)(T0 + 12 + q * 4);
            float4 c = *(const float4*)(T1 + 12 + q * 4);
            wp[q * 4 + 0] = fmaf(f, c.x - a.x, a.x);
            wp[q * 4 + 1] = fmaf(f, c.y - a.y, a.y);
            wp[q * 4 + 2] = fmaf(f, c.z - a.z, a.z);
            wp[q * 4 + 3] = fmaf(f, c.w - a.w, a.w);
        }
        float xp[12];
#pragma unroll
        for (int i = 0; i < 3; ++i) ((float4*)xp)[i] = ((const float4*)(rr + 4))[i];
        float* op0 = b;       // 4
        float* op1 = b + 4;   // 12
        float* op2 = b + 16;  // 20
#pragma unroll
        for (int t = 0; t < 36; ++t) b[t] = 0.f;
#pragma unroll
        for (int u = 0; u < 3; ++u) {
            float x0 = xp[u*3+0] * fm, x1 = xp[u*3+1] * fm, x2 = xp[u*3+2] * fm;
            float dot = x0 * sh1 + x1 * sh2 + x2 * sh3;
            float ya0 = R10 * (x0 * sh3 + x2 * sh1);
            float ya1 = R10 * (x0 * sh2 + x1 * sh1);
            float ya2 = R30 * (2.f * x1 * sh2 - x0 * sh1 - x2 * sh3);
            float ya3 = R10 * (x1 * sh3 + x2 * sh2);
            float ya4 = R10 * (x2 * sh3 - x0 * sh1);
            float yb0 = R10 * (x2 * sh4 + x1 * sh5 - x0 * sh8) - R30 * x0 * sh6;
            float yb1 = R10 * (x0 * sh5 + x2 * sh7) + R30x2 * x1 * sh6;
            float yb2 = R10 * (x0 * sh4 + x1 * sh7 + x2 * sh8) - R30 * x2 * sh6;
#pragma unroll
            for (int w = 0; w < 4; ++w) {
                float wa = wp[u * 4 + w];
                float wb = wp[12 + u * 4 + w];
                float wc = wp[24 + u * 4 + w];
                float wd2 = wp[36 + u * 4 + w];
                op0[w] = fmaf(dot, wb, op0[w]);
                op1[w * 3 + 0] = fmaf(x0, wa, fmaf(yb0, wd2, op1[w * 3 + 0]));
                op1[w * 3 + 1] = fmaf(x1, wa, fmaf(yb1, wd2, op1[w * 3 + 1]));
                op1[w * 3 + 2] = fmaf(x2, wa, fmaf(yb2, wd2, op1[w * 3 + 2]));
                op2[w * 5 + 0] = fmaf(ya0, wc, op2[w * 5 + 0]);
                op2[w * 5 + 1] = fmaf(ya1, wc, op2[w * 5 + 1]);
                op2[w * 5 + 2] = fmaf(ya2, wc, op2[w * 5 + 2]);
                op2[w * 5 + 3] = fmaf(ya3, wc, op2[w * 5 + 3]);
                op2[w * 5 + 4] = fmaf(ya4, wc, op2[w * 5 + 4]);
            }
        }
        segscan36(b, dist);
        emit(36);
    }

    // ================= D path (table cols 60..139 -> out 72..107) =================
    {
        float wd[80];
#pragma unroll
        for (int q = 0; q < 20; ++q) {
            float4 a = *(const float4*)(T0 + 60 + q * 4);
            float4 c = *(const float4*)(T1 + 60 + q * 4);
            wd[q * 4 + 0] = fmaf(f, c.x - a.x, a.x);
            wd[q * 4 + 1] = fmaf(f, c.y - a.y, a.y);
            wd[q * 4 + 2] = fmaf(f, c.z - a.z, a.z);
            wd[q * 4 + 3] = fmaf(f, c.w - a.w, a.w);
        }
        float xd[28];
#pragma unroll
        for (int i = 0; i < 7; ++i) ((float4*)xd)[i] = ((const float4*)(rr + 16))[i];
        float* od0 = b;       // 4
        float* od1 = b + 4;   // 12
        float* od2 = b + 16;  // 20
#pragma unroll
        for (int t = 0; t < 36; ++t) b[t] = 0.f;
#pragma unroll
        for (int u = 0; u < 5; ++u) {
            float x0 = xd[u*5+0] * fm, x1 = xd[u*5+1] * fm, x2 = xd[u*5+2] * fm;
            float x3 = xd[u*5+3] * fm, x4 = xd[u*5+4] * fm;
            float dot = x0 * sh4 + x1 * sh5 + x2 * sh6 + x3 * sh7 + x4 * sh8;
            float yb0 = R10 * (x0 * sh3 + x1 * sh2 - x4 * sh1) - R30 * x2 * sh1;
            float yb1 = R10 * (x1 * sh1 + x3 * sh3) + R30x2 * x2 * sh2;
            float yb2 = R10 * (x0 * sh1 + x3 * sh2 + x4 * sh3) - R30 * x2 * sh3;
            float yc0 = CCA * (x2 * sh4 + x0 * sh6) - CCB * (x1 * sh7 + x3 * sh5);
            float yc1 = CCB * (x1 * sh8 + x4 * sh5 - x0 * sh7 - x3 * sh4)
                      - CCC * (x1 * sh6 + x2 * sh5);
            float yc2 = CCA * (x0 * sh4 - x2 * sh6 + x4 * sh8)
                      - CCC * (x1 * sh5 + x3 * sh7);
            float yc3 = -CCB * (x0 * sh5 + x1 * sh4 + x3 * sh8 + x4 * sh7)
                      - CCC * (x2 * sh7 + x3 * sh6);
            float yc4 = CCB * (x1 * sh5 - x3 * sh7) + CCA * (x2 * sh8 + x4 * sh6);
#pragma unroll
            for (int w = 0; w < 4; ++w) {
                float wa = wd[u * 4 + w];
                float wb = wd[20 + u * 4 + w];
                float wc = wd[40 + u * 4 + w];
                float we = wd[60 + u * 4 + w];
                od0[w] = fmaf(dot, wc, od0[w]);
                od1[w * 3 + 0] = fmaf(yb0, wb, od1[w * 3 + 0]);
                od1[w * 3 + 1] = fmaf(yb1, wb, od1[w * 3 + 1]);
                od1[w * 3 + 2] = fmaf(yb2, wb, od1[w * 3 + 2]);
                od2[w * 5 + 0] = fmaf(x0, wa, fmaf(yc0, we, od2[w * 5 + 0]));
                od2[w * 5 + 1] = fmaf(x1, wa, fmaf(yc1, we, od2[w * 5 + 1]));
                od2[w * 5 + 2] = fmaf(x2, wa, fmaf(yc2, we, od2[w * 5 + 2]));
                od2[w * 5 + 3] = fmaf(x3, wa, fmaf(yc3, we, od2[w * 5 + 3]));
                od2[w * 5 + 4] = fmaf(x4, wa, fmaf(yc4, we, od2[w * 5 + 4]));
            }
        }
        segscan36(b, dist);
        emit(72);
    }
}

// ============ fallback: R1 atomic kernel (verified; no workspace needed) ============
template<int M>
__device__ __forceinline__ void fc_eval(const float* sW1T, const float* sW2,
                                        const float emb[12], float* acc)
{
#pragma unroll
    for (int m = 0; m < M; ++m) acc[m] = 0.f;
#pragma unroll 2
    for (int j = 0; j < 64; ++j) {
        const float4* w1r = (const float4*)(sW1T + j * 12);
        float4 A = w1r[0], B = w1r[1], C = w1r[2];
        float t = A.x*emb[0] + A.y*emb[1] + A.z*emb[2] + A.w*emb[3]
                + B.x*emb[4] + B.y*emb[5] + B.z*emb[6] + B.w*emb[7]
                + C.x*emb[8] + C.y*emb[9];
        t = fmaxf(t, 0.f);
        const float4* w2r = (const float4*)(sW2 + j * M);
#pragma unroll
        for (int q = 0; q < M / 4; ++q) {
            float4 V = w2r[q];
            acc[4*q+0] = fmaf(t, V.x, acc[4*q+0]);
            acc[4*q+1] = fmaf(t, V.y, acc[4*q+1]);
            acc[4*q+2] = fmaf(t, V.z, acc[4*q+2]);
            acc[4*q+3] = fmaf(t, V.w, acc[4*q+3]);
        }
    }
}

__global__ __launch_bounds__(TPB) void eqconv_edge_kernel_atomic(
    const float* __restrict__ f_in,
    const int*   __restrict__ eidx,
    const float* __restrict__ pos,
    const float* __restrict__ W1s_g, const float* __restrict__ W2s_g,
    const float* __restrict__ W1p_g, const float* __restrict__ W2p_g,
    const float* __restrict__ W1d_g, const float* __restrict__ W2d_g,
    float* __restrict__ out,
    int E, float snorm)
{
    __shared__ __align__(16) float smem[11264];
    float* tW1s = smem;
    float* tW1p = smem + 768;
    float* tW1d = smem + 1536;
    float* sW2s = smem + 2304;
    float* sW2p = smem + 3072;
    float* sW2d = smem + 6144;

    const int tid = threadIdx.x;
    const float base = 0.05590169943749474f * snorm;

    for (int idx = tid; idx < 768; idx += TPB) {
        int j = idx / 12, i = idx - j * 12;
        tW1s[idx] = (i < 10) ? W1s_g[i * 64 + j] : 0.f;
        tW1p[idx] = (i < 10) ? W1p_g[i * 64 + j] : 0.f;
        tW1d[idx] = (i < 10) ? W1d_g[i * 64 + j] : 0.f;
    }
    for (int idx = tid; idx < 768; idx += TPB)
        sW2s[idx] = W2s_g[idx] * base;
    for (int idx = tid; idx < 3072; idx += TPB) {
        int m = idx % 48;
        float k = (m < 12) ? 0.40824829046386307f
                : (m < 24) ? 0.33333333333333333f
                : (m < 36) ? 1.29099444873580560f
                           : 0.70710678118654752f;
        sW2p[idx] = W2p_g[idx] * (base * k);
    }
    for (int idx = tid; idx < 5120; idx += TPB) {
        int m = idx % 80;
        float k = (m < 20) ? 0.31622776601683794f
                : (m < 40) ? 0.77459666924148340f
                : (m < 60) ? 0.2f
                           : 0.70710678118654752f;
        sW2d[idx] = W2d_g[idx] * (base * k);
    }
    __syncthreads();

    int e = blockIdx.x * TPB + tid;
    if (e >= E) return;

    const int row = eidx[e];
    const int col = eidx[E + e];

    float ex = pos[row * 3 + 0] - pos[col * 3 + 0];
    float ey = pos[row * 3 + 1] - pos[col * 3 + 1];
    float ez = pos[row * 3 + 2] - pos[col * 3 + 2];
    float r = sqrtf(ex * ex + ey * ey + ez * ez + 1e-12f);
    float rinv = 1.0f / r;
    float x = ex * rinv, y = ey * rinv, z = ez * rinv;

    float sh1 = 1.7320508075688772f * x;
    float sh2 = 1.7320508075688772f * y;
    float sh3 = 1.7320508075688772f * z;
    float sh4 = 3.8729833462074170f * x * z;
    float sh5 = 3.8729833462074170f * x * y;
    float sh6 = 1.1180339887498949f * (2.f * y * y - x * x - z * z);
    float sh7 = 3.8729833462074170f * y * z;
    float sh8 = 1.9364916731037085f * (z * z - x * x);

    float emb[12];
    {
        const float F = (float)(1.14136 * 7.38905609893065 * 3.1622776601683795);
        const float inv_step = 2.2f;
#pragma unroll
        for (int i = 0; i < 10; ++i) {
            float v = (float)(i + 1) * (5.0f / 11.0f);
            float d = (r - v) * inv_step;
            float d2 = d * d;
            emb[i] = (d2 < 1.0f) ? F * expf(-2.0f / (1.0f - d2)) : 0.f;
        }
        emb[10] = 0.f; emb[11] = 0.f;
    }

    const float* fr = f_in + (size_t)row * 162;
    float* o = out + (size_t)col * 108;

    {
        float ws[12];
        fc_eval<12>(tW1s, sW2s, emb, ws);
        float2 v0 = *(const float2*)(fr);
        float X = v0.x + v0.y;
#pragma unroll
        for (int w = 0; w < 4; ++w) {
            atomAddF(o + w, X * ws[w]);
            float t1 = X * ws[4 + w];
            atomAddF(o + 4 + w * 3 + 0, t1 * sh1);
            atomAddF(o + 4 + w * 3 + 1, t1 * sh2);
            atomAddF(o + 4 + w * 3 + 2, t1 * sh3);
            float t2 = X * ws[8 + w];
            atomAddF(o + 16 + w * 5 + 0, t2 * sh4);
            atomAddF(o + 16 + w * 5 + 1, t2 * sh5);
            atomAddF(o + 16 + w * 5 + 2, t2 * sh6);
            atomAddF(o + 16 + w * 5 + 3, t2 * sh7);
            atomAddF(o + 16 + w * 5 + 4, t2 * sh8);
        }
    }
    {
        float wp[48];
        fc_eval<48>(tW1p, sW2p, emb, wp);
        float op0[4] = {0.f,0.f,0.f,0.f};
        float op1[12], op2[20];
#pragma unroll
        for (int t = 0; t < 12; ++t) op1[t] = 0.f;
#pragma unroll
        for (int t = 0; t < 20; ++t) op2[t] = 0.f;
#pragma unroll
        for (int u = 0; u < 3; ++u) {
            float2 a0 = *(const float2*)(fr + ((1 + u) * 9 + 1) * 2);
            float2 a1 = *(const float2*)(fr + ((1 + u) * 9 + 2) * 2);
            float2 a2 = *(const float2*)(fr + ((1 + u) * 9 + 3) * 2);
            float x0 = a0.x + a0.y, x1 = a1.x + a1.y, x2 = a2.x + a2.y;
            float dot = x0 * sh1 + x1 * sh2 + x2 * sh3;
            float ya0 = R10 * (x0 * sh3 + x2 * sh1);
            float ya1 = R10 * (x0 * sh2 + x1 * sh1);
            float ya2 = R30 * (2.f * x1 * sh2 - x0 * sh1 - x2 * sh3);
            float ya3 = R10 * (x1 * sh3 + x2 * sh2);
            float ya4 = R10 * (x2 * sh3 - x0 * sh1);
            float yb0 = R10 * (x2 * sh4 + x1 * sh5 - x0 * sh8) - R30 * x0 * sh6;
            float yb1 = R10 * (x0 * sh5 + x2 * sh7) + R30x2 * x1 * sh6;
            float yb2 = R10 * (x0 * sh4 + x1 * sh7 + x2 * sh8) - R30 * x2 * sh6;
#pragma unroll
            for (int w = 0; w < 4; ++w) {
                float wa = wp[u * 4 + w];
                float wb = wp[12 + u * 4 + w];
                float wc = wp[24 + u * 4 + w];
                float wd2 = wp[36 + u * 4 + w];
                op0[w] = fmaf(dot, wb, op0[w]);
                op1[w * 3 + 0] = fmaf(x0, wa, fmaf(yb0, wd2, op1[w * 3 + 0]));
                op1[w * 3 + 1] = fmaf(x1, wa, fmaf(yb1, wd2, op1[w * 3 + 1]));
                op1[w * 3 + 2] = fmaf(x2, wa, fmaf(yb2, wd2, op1[w * 3 + 2]));
                op2[w * 5 + 0] = fmaf(ya0, wc, op2[w * 5 + 0]);
                op2[w * 5 + 1] = fmaf(ya1, wc, op2[w * 5 + 1]);
                op2[w * 5 + 2] = fmaf(ya2, wc, op2[w * 5 + 2]);
                op2[w * 5 + 3] = fmaf(ya3, wc, op2[w * 5 + 3]);
                op2[w * 5 + 4] = fmaf(ya4, wc, op2[w * 5 + 4]);
            }
        }
#pragma unroll
        for (int w = 0; w < 4; ++w) atomAddF(o + 36 + w, op0[w]);
#pragma unroll
        for (int t = 0; t < 12; ++t) atomAddF(o + 40 + t, op1[t]);
#pragma unroll
        for (int t = 0; t < 20; ++t) atomAddF(o + 52 + t, op2[t]);
    }
    {
        float wd[80];
        fc_eval<80>(tW1d, sW2d, emb, wd);
        float od0[4] = {0.f,0.f,0.f,0.f};
        float od1[12], od2[20];
#pragma unroll
        for (int t = 0; t < 12; ++t) od1[t] = 0.f;
#pragma unroll
        for (int t = 0; t < 20; ++t) od2[t] = 0.f;
#pragma unroll
        for (int u = 0; u < 5; ++u) {
            float2 b0 = *(const float2*)(fr + ((4 + u) * 9 + 4) * 2);
            float2 b1 = *(const float2*)(fr + ((4 + u) * 9 + 5) * 2);
            float2 b2 = *(const float2*)(fr + ((4 + u) * 9 + 6) * 2);
            float2 b3 = *(const float2*)(fr + ((4 + u) * 9 + 7) * 2);
            float2 b4 = *(const float2*)(fr + ((4 + u) * 9 + 8) * 2);
            float x0 = b0.x + b0.y, x1 = b1.x + b1.y, x2 = b2.x + b2.y;
            float x3 = b3.x + b3.y, x4 = b4.x + b4.y;
            float dot = x0 * sh4 + x1 * sh5 + x2 * sh6 + x3 * sh7 + x4 * sh8;
            float yb0 = R10 * (x0 * sh3 + x1 * sh2 - x4 * sh1) - R30 * x2 * sh1;
            float yb1 = R10 * (x1 * sh1 + x3 * sh3) + R30x2 * x2 * sh2;
            float yb2 = R10 * (x0 * sh1 + x3 * sh2 + x4 * sh3) - R30 * x2 * sh3;
            float yc0 = CCA * (x2 * sh4 + x0 * sh6) - CCB * (x1 * sh7 + x3 * sh5);
            float yc1 = CCB * (x1 * sh8 + x4 * sh5 - x0 * sh7 - x3 * sh4)
                      - CCC * (x1 * sh6 + x2 * sh5);
            float yc2 = CCA * (x0 * sh4 - x2 * sh6 + x4 * sh8)
                      - CCC * (x1 * sh5 + x3 * sh7);
            float yc3 = -CCB * (x0 * sh5 + x1 * sh4 + x3 * sh8 + x4 * sh7)
                      - CCC * (x2 * sh7 + x3 * sh6);
            float yc4 = CCB * (x1 * sh5 - x3 * sh7) + CCA * (x2 * sh8 + x4 * sh6);
#pragma unroll
            for (int w = 0; w < 4; ++w) {
                float wa = wd[u * 4 + w];
                float wb = wd[20 + u * 4 + w];
                float wc = wd[40 + u * 4 + w];
                float we = wd[60 + u * 4 + w];
                od0[w] = fmaf(dot, wc, od0[w]);
                od1[w * 3 + 0] = fmaf(yb0, wb, od1[w * 3 + 0]);
                od1[w * 3 + 1] = fmaf(yb1, wb, od1[w * 3 + 1]);
                od1[w * 3 + 2] = fmaf(yb2, wb, od1[w * 3 + 2]);
                od2[w * 5 + 0] = fmaf(x0, wa, fmaf(yc0, we, od2[w * 5 + 0]));
                od2[w * 5 + 1] = fmaf(x1, wa, fmaf(yc1, we, od2[w * 5 + 1]));
                od2[w * 5 + 2] = fmaf(x2, wa, fmaf(yc2, we, od2[w * 5 + 2]));
                od2[w * 5 + 3] = fmaf(x3, wa, fmaf(yc3, we, od2[w * 5 + 3]));
                od2[w * 5 + 4] = fmaf(x4, wa, fmaf(yc4, we, od2[w * 5 + 4]));
            }
        }
#pragma unroll
        for (int w = 0; w < 4; ++w) atomAddF(o + 72 + w, od0[w]);
#pragma unroll
        for (int t = 0; t < 12; ++t) atomAddF(o + 76 + t, od1[t]);
#pragma unroll
        for (int t = 0; t < 20; ++t) atomAddF(o + 88 + t, od2[t]);
    }
}

extern "C" void kernel_launch(void* const* d_in, const int* in_sizes, int n_in,
                              void* d_out, int out_size, void* d_ws, size_t ws_size,
                              hipStream_t stream) {
    const float* f_in = (const float*)d_in[0];
    const int*   eidx = (const int*)d_in[1];
    const float* pos  = (const float*)d_in[2];
    const float* W1s = (const float*)d_in[5];
    const float* W2s = (const float*)d_in[6];
    const float* W1p = (const float*)d_in[7];
    const float* W2p = (const float*)d_in[8];
    const float* W1d = (const float*)d_in[9];
    const float* W2d = (const float*)d_in[10];

    const int E = in_sizes[1] / 2;
    const int N = in_sizes[0] / 162;
    const float snorm = (float)(1.0 / sqrt((double)E / (double)N));
    const float base = 0.05590169943749474f * snorm;   // sqrt2/(8*sqrt10) * snorm
    const int eBlocks = (E + 255) / 256;
    const int numTiles = (E + TPB - 1) / TPB;

    // ws: edges int2[E] | cursor[N] (histogram+in-place scan) | rec[44N] | table[(NB+1)*TROW]
    const size_t edgesBytes = (size_t)E * sizeof(int2);
    const size_t curOff  = edgesBytes;
    const size_t recOff  = (curOff + (size_t)N * sizeof(int) + 15) & ~((size_t)15);
    const size_t tabOff  = (recOff + (size_t)N * 44 * sizeof(float) + 15) & ~((size_t)15);

    // dynamic table size: prefer 2048 bins, degrade if workspace is tight
    int NB = 0;
    if (ws_size > tabOff) {
        size_t rows = (ws_size - tabOff) / (TROW * sizeof(float));
        if (rows >= 513) NB = (int)((rows - 1) < 2048 ? (rows - 1) : 2048);
    }

    if (NB >= 512) {
        int2*  edges  = (int2*)d_ws;
        int*   cursor = (int*)((char*)d_ws + curOff);
        float* rec    = (float*)((char*)d_ws + recOff);
        float* table  = (float*)((char*)d_ws + tabOff);
        const float Delta = 5.0f / (float)NB;
        const float invDelta = (float)NB / 5.0f;

        hipMemsetAsync(cursor, 0, (size_t)N * sizeof(int), stream);
        hipMemsetAsync(d_out, 0, (size_t)out_size * sizeof(float), stream);
        build_rec_count<<<eBlocks, 256, 0, stream>>>(f_in, pos, eidx, rec, cursor, N, E);
        build_table<<<NB + 1, 256, 0, stream>>>(W1s, W2s, W1p, W2p, W1d, W2d,
                                                table, Delta, base);
        scan_kernel<<<1, 1024, 0, stream>>>(cursor, N);
        permute_kernel<<<eBlocks, 256, 0, stream>>>(eidx, cursor, edges, E);
        fused3_kernel<<<numTiles, TPB, 0, stream>>>(
            rec, edges, table, (float*)d_out, E, NB, invDelta);
    } else {
        hipMemsetAsync(d_out, 0, (size_t)out_size * sizeof(float), stream);
        eqconv_edge_kernel_atomic<<<eBlocks, TPB, 0, stream>>>(
            f_in, eidx, pos, W1s, W2s, W1p, W2p, W1d, W2d,
            (float*)d_out, E, snorm);
    }
}